// Round 8
// baseline (502.655 us; speedup 1.0000x reference)
//
#include <hip/hip_runtime.h>

#define LRELU_ALPHA 0.2f

typedef __attribute__((ext_vector_type(8))) short short8;
typedef __attribute__((ext_vector_type(4))) float float4v;
typedef __attribute__((ext_vector_type(2))) float f32x2;

__device__ __forceinline__ unsigned short f2bf(float f) {
  union { float f; unsigned u; } x; x.f = f;
  unsigned r = (x.u + 0x7fff + ((x.u >> 16) & 1)) >> 16;
  return (unsigned short)r;
}
__device__ __forceinline__ float bflo(unsigned u) {
  union { unsigned u; float f; } x; x.u = u << 16; return x.f;
}
__device__ __forceinline__ float bfhi(unsigned u) {
  union { unsigned u; float f; } x; x.u = u & 0xffff0000u; return x.f;
}
__device__ __forceinline__ f32x2 bfpair(unsigned u) {
  return (f32x2){bflo(u), bfhi(u)};
}

// =============================== Phase A: CSR build ===============================

__global__ __launch_bounds__(256) void k_count(const int* __restrict__ dst,
                                               int* __restrict__ cnt, int E) {
  int e = blockIdx.x * 256 + threadIdx.x;
  if (e < E) atomicAdd(&cnt[dst[e]], 1);
}

__global__ __launch_bounds__(1024) void k_scan1(const int* __restrict__ cnt,
                                                int* __restrict__ lscan,
                                                int* __restrict__ bsum, int N) {
  __shared__ int sm[1024];
  int t = threadIdx.x;
  int base = blockIdx.x * 1024;
  int v = (base + t < N) ? cnt[base + t] : 0;
  sm[t] = v;
  __syncthreads();
  for (int off = 1; off < 1024; off <<= 1) {
    int x = (t >= off) ? sm[t - off] : 0;
    __syncthreads();
    sm[t] += x;
    __syncthreads();
  }
  if (base + t < N) lscan[base + t] = sm[t] - v;
  if (t == 1023) bsum[blockIdx.x] = sm[1023];
}

// one-wave shfl scan (nb <= 64)
__global__ __launch_bounds__(64) void k_scan2(int* __restrict__ bsum,
                                              int* __restrict__ rowptrN, int nb) {
  int t = threadIdx.x;
  int v = (t < nb) ? bsum[t] : 0;
  int orig = v;
  for (int off = 1; off < 64; off <<= 1) {
    int y = __shfl_up(v, off, 64);
    if (t >= off) v += y;
  }
  if (t < nb) bsum[t] = v - orig;
  if (t == 63) *rowptrN = v;
}

__global__ __launch_bounds__(1024) void k_scan3(int* __restrict__ rowptr,
                                                int* __restrict__ cur,
                                                const int* __restrict__ bsum, int N) {
  int i = blockIdx.x * 1024 + threadIdx.x;
  if (i < N) {
    int v = rowptr[i] + bsum[blockIdx.x];
    rowptr[i] = v;
    cur[i] = v;
  }
}

__global__ __launch_bounds__(256) void k_scatter(const int* __restrict__ src,
                                                 const int* __restrict__ dst,
                                                 const float* __restrict__ w,
                                                 int* __restrict__ cur,
                                                 uint2* __restrict__ edata, int E) {
  int e = blockIdx.x * 256 + threadIdx.x;
  if (e < E) {
    int d = dst[e];
    int p = atomicAdd(&cur[d], 1);
    edata[p] = make_uint2((unsigned)src[e], __float_as_uint(w[e]));
  }
}

// =============================== weight packing ===============================
// W0catT bf16 [256][128], ROW-PERMUTED for interleaved feat0i:
//   row n: q=n>>2, r=n&3. r<2 -> GAT col o=2q+r (h=o>>4,f=o&15): W0[h,k,f]
//                        r>=2 -> GCN col j=2q+(r-2): gcn_W0[k][j]
// logitW  fp32 [128][16] : c<8: va0_src[k][h=c]; c>=8: va0_dst[k][h=c-8]
// gw1T    bf16 [128][128]: gw1T[n][k] = gcn_W1[k][n]
// va1T    bf16 [16][128] : c<8: W1[h=c]@a1_src; c>=8: W1[h]@a1_dst
// WstackT bf16 [128][1024]: WstackT[n][h*128+k] = W1[h][k][n] * 0.125
__global__ __launch_bounds__(256) void k_pack(const float* __restrict__ W0,
                                              const float* __restrict__ a0s,
                                              const float* __restrict__ a0d,
                                              const float* __restrict__ W1,
                                              const float* __restrict__ a1s,
                                              const float* __restrict__ a1d,
                                              const float* __restrict__ gw0,
                                              const float* __restrict__ gw1,
                                              unsigned short* __restrict__ W0catT,
                                              float* __restrict__ logitW,
                                              unsigned short* __restrict__ gw1T,
                                              unsigned short* __restrict__ va1T,
                                              unsigned short* __restrict__ WstackT) {
  int idx = blockIdx.x * 256 + threadIdx.x;
  if (idx < 32768) {
    int n = idx >> 7, k = idx & 127;
    int q = n >> 2, r = n & 3;
    float v;
    if (r < 2) {
      int o = 2 * q + r;
      int h = o >> 4, f = o & 15;
      v = W0[h * 2048 + k * 16 + f];
    } else {
      int j = 2 * q + (r - 2);
      v = gw0[k * 128 + j];
    }
    W0catT[idx] = f2bf(v);
  } else if (idx < 34816) {
    int j = idx - 32768;
    int k = j >> 4, c = j & 15;
    int h = (c < 8) ? c : c - 8;
    const float* a = (c < 8) ? a0s : a0d;
    float s = 0.f;
    for (int f = 0; f < 16; ++f) s += W0[h * 2048 + k * 16 + f] * a[h * 16 + f];
    logitW[j] = s;
  } else if (idx < 51200) {
    int j = idx - 34816;
    int n = j >> 7, k = j & 127;
    gw1T[j] = f2bf(gw1[k * 128 + n]);
  } else if (idx < 53248) {
    int j = idx - 51200;
    int c = j >> 7, k = j & 127;
    int h = c & 7;
    const float* a = (c < 8) ? a1s : a1d;
    float s = 0.f;
    for (int f = 0; f < 128; ++f) s += W1[h * 16384 + k * 128 + f] * a[h * 128 + f];
    va1T[j] = f2bf(s);
  } else if (idx < 184320) {
    int j = idx - 53248;
    int n = j >> 10, kk = j & 1023;
    int h = kk >> 7, k = kk & 127;
    WstackT[j] = f2bf(W1[h * 16384 + k * 128 + n] * 0.125f);
  }
}

// fused: xb = bf16(x), logit0[N,16] = x @ logitW; 16 rows per block
__global__ __launch_bounds__(256) void k_prep(const float* __restrict__ x,
                                              const float* __restrict__ logitW,
                                              unsigned short* __restrict__ xb,
                                              float* __restrict__ logit0, int N) {
  __shared__ float sm[16][132];
  __shared__ float sw[2048];
  int t = threadIdx.x;
  int base = blockIdx.x * 16;
  int r = t >> 4, cc = (t & 15) * 8;
  const float* xr = x + (size_t)(base + r) * 128 + cc;
  float4 v0 = *(const float4*)xr;
  float4 v1 = *(const float4*)(xr + 4);
  ushort4 o0 = {f2bf(v0.x), f2bf(v0.y), f2bf(v0.z), f2bf(v0.w)};
  ushort4 o1 = {f2bf(v1.x), f2bf(v1.y), f2bf(v1.z), f2bf(v1.w)};
  *(ushort4*)(xb + (size_t)(base + r) * 128 + cc) = o0;
  *(ushort4*)(xb + (size_t)(base + r) * 128 + cc + 4) = o1;
  *(float4*)&sm[r][cc] = v0;
  *(float4*)&sm[r][cc + 4] = v1;
  *(float4*)&sw[t * 8] = *(const float4*)(logitW + t * 8);
  *(float4*)&sw[t * 8 + 4] = *(const float4*)(logitW + t * 8 + 4);
  __syncthreads();
  int c = t & 15;
  float acc = 0.f;
#pragma unroll
  for (int k = 0; k < 128; ++k) acc += sm[r][k] * sw[k * 16 + c];
  logit0[(size_t)(base + r) * 16 + c] = acc;
}

// =============================== edge-weight precompute ===============================
// wave per dst. logits[N][16]: cols 0..7 src-side (es), 8..15 dst-side (ed).
// lane (j8=lane>>3, h=lane&7): edge beg+base+j8, head h.
// writes pedge[E][8] bf16 (raw exp values) + linv[N][8] fp32 = (l>0 ? 1/l : 0), l exact fp32.
__global__ __launch_bounds__(256) void k_pedge(const float* __restrict__ logits,
                                               const uint2* __restrict__ edata,
                                               const int* __restrict__ rowptr,
                                               unsigned short* __restrict__ pedge,
                                               float* __restrict__ linv, int N) {
  int wave = threadIdx.x >> 6, lane = threadIdx.x & 63;
  int d = blockIdx.x * 4 + wave;
  if (d >= N) return;
  int j8 = lane >> 3, h = lane & 7;
  float edv = logits[(size_t)d * 16 + 8 + h];
  int beg = rowptr[d], end = rowptr[d + 1];
  float lsum = 0.f;
  for (int ii = beg + j8; ii < end; ii += 8) {
    unsigned s = edata[ii].x;
    float es = logits[(size_t)s * 16 + h];
    float lg = es + edv;
    lg = lg > 0.f ? lg : LRELU_ALPHA * lg;
    float p = __expf(fminf(lg, 80.f));
    lsum += p;
    pedge[(size_t)ii * 8 + h] = f2bf(p);
  }
  lsum += __shfl_xor(lsum, 8, 64);
  lsum += __shfl_xor(lsum, 16, 64);
  lsum += __shfl_xor(lsum, 32, 64);
  if (lane < 8) linv[(size_t)d * 8 + h] = lsum > 0.f ? 1.f / lsum : 0.f;
}

// =============================== bf16 MFMA GEMM ===============================
// C = A[M,K] @ BT[Ncols,K]^T. EPI: 0 plain, 1 max(acc, bf16 aux), 2 interleaved-xh write
template <int NT, int OUT_BF16, int EPI>
__global__ __launch_bounds__(256) void k_mgemm(const unsigned short* __restrict__ A, int lda,
                                               const unsigned short* __restrict__ BT, int ldb,
                                               void* __restrict__ Cv, int ldc,
                                               const void* __restrict__ aux,
                                               int M, int Ncols, int K) {
  __shared__ unsigned short As[64][64];
  __shared__ unsigned short Bs[NT * 16][64];
  int tid = threadIdx.x;
  int w = tid >> 6, lane = tid & 63;
  int quad = lane >> 4, l16 = lane & 15;
  int row0 = blockIdx.x * 64;
  int c0 = blockIdx.y * (NT * 16);
  float4v acc[NT];
#pragma unroll
  for (int t = 0; t < NT; ++t) acc[t] = (float4v){0.f, 0.f, 0.f, 0.f};

  for (int k0 = 0; k0 < K; k0 += 64) {
    __syncthreads();
#pragma unroll
    for (int i = 0; i < 2; ++i) {
      int c = tid + i * 256;
      int r = c >> 3, kc = c & 7;
      uint4 v = {0u, 0u, 0u, 0u};
      int gr = row0 + r;
      if (gr < M) v = *(const uint4*)(A + (size_t)gr * lda + k0 + kc * 8);
      *(uint4*)(&As[r][(kc ^ (r & 7)) * 8]) = v;
    }
#pragma unroll
    for (int i = 0; i < (NT * 128 + 255) / 256; ++i) {
      int c = tid + i * 256;
      if (c < NT * 128) {
        int n = c >> 3, kc = c & 7;
        uint4 v = {0u, 0u, 0u, 0u};
        int gn = c0 + n;
        if (gn < Ncols) v = *(const uint4*)(BT + (size_t)gn * ldb + k0 + kc * 8);
        *(uint4*)(&Bs[n][(kc ^ (n & 7)) * 8]) = v;
      }
    }
    __syncthreads();
#pragma unroll
    for (int ks = 0; ks < 2; ++ks) {
      int m = w * 16 + l16;
      int ga = (ks * 4 + quad) ^ (m & 7);
      short8 a = *(const short8*)(&As[m][ga * 8]);
#pragma unroll
      for (int t = 0; t < NT; ++t) {
        int n = t * 16 + l16;
        int gb = (ks * 4 + quad) ^ (n & 7);
        short8 b = *(const short8*)(&Bs[n][gb * 8]);
        acc[t] = __builtin_amdgcn_mfma_f32_16x16x32_bf16(a, b, acc[t], 0, 0, 0);
      }
    }
  }
#pragma unroll
  for (int t = 0; t < NT; ++t) {
    int cc = c0 + t * 16 + l16;
    if (cc >= Ncols) continue;
#pragma unroll
    for (int i = 0; i < 4; ++i) {
      int rr = row0 + w * 16 + quad * 4 + i;
      if (rr >= M) continue;
      float v = acc[t][i];
      if (EPI == 1) {
        unsigned short us = ((const unsigned short*)aux)[(size_t)rr * ldc + cc];
        v = fmaxf(v, bflo((unsigned)us));
      }
      if (EPI == 2) {
        // h1 -> xh interleaved: col cc -> 4*(cc>>1) + 2 + (cc&1)
        ((unsigned short*)Cv)[(size_t)rr * 256 + 4 * (cc >> 1) + 2 + (cc & 1)] = f2bf(v);
      } else if (OUT_BF16)
        ((unsigned short*)Cv)[(size_t)rr * ldc + cc] = f2bf(v);
      else
        ((float*)Cv)[(size_t)rr * ldc + cc] = v;
    }
  }
}

// =============================== Phase C: layer-0 aggregation ===============================
// wave per dst. feat0i row interleaved: bf16 cols 4q,4q+1 = GAT dims 2q,2q+1;
// 4q+2,4q+3 = GCN dims. lane q covers dims 2q,2q+1 (head=q>>3).
// p precomputed (pedge/linv) -> inner loop is pure gather+FMA.
__global__ __launch_bounds__(256) void k_agg0(const unsigned short* __restrict__ feat0i,
                                              const int* __restrict__ rowptr,
                                              const uint2* __restrict__ edata,
                                              const unsigned short* __restrict__ pedge,
                                              const float* __restrict__ linv,
                                              unsigned short* __restrict__ x1c,
                                              unsigned short* __restrict__ x2,
                                              unsigned short* __restrict__ xh, int N) {
  __shared__ uint2 swl[4][64];
  __shared__ float pl[4][512];
  int wave = threadIdx.x >> 6, lane = threadIdx.x & 63;
  int d = blockIdx.x * 4 + wave;
  if (d >= N) return;
  int head = lane >> 3;
  int beg = rowptr[d], end = rowptr[d + 1], deg = end - beg;
  float wsum = 0.f;
  f32x2 a2 = {0.f, 0.f}, g2 = {0.f, 0.f};
  for (int base = 0; base < deg; base += 64) {
    int idx = beg + base + lane;
    bool valid = idx < end;
    uint2 sv = make_uint2(0u, 0u);
    float4 pa = {0.f, 0.f, 0.f, 0.f}, pb = {0.f, 0.f, 0.f, 0.f};
    if (valid) {
      sv = edata[idx];
      ushort4 q0 = *(const ushort4*)(pedge + (size_t)idx * 8);
      ushort4 q1 = *(const ushort4*)(pedge + (size_t)idx * 8 + 4);
      pa = make_float4(bflo(q0.x), bflo(q0.y), bflo(q0.z), bflo(q0.w));
      pb = make_float4(bflo(q1.x), bflo(q1.y), bflo(q1.z), bflo(q1.w));
    }
    swl[wave][lane] = sv;
    *(float4*)&pl[wave][lane * 8] = pa;
    *(float4*)&pl[wave][lane * 8 + 4] = pb;
    int ng = deg - base; if (ng > 64) ng = 64;
    int groups = (ng + 7) >> 3;
    for (int g = 0; g < groups; ++g) {
#pragma unroll
      for (int j = 0; j < 8; ++j) {
        int e = g * 8 + j;
        uint2 sw = swl[wave][e];
        float pj = pl[wave][e * 8 + head];
        float wj = __uint_as_float(sw.y);
        uint2 u = *(const uint2*)(feat0i + (size_t)sw.x * 256 + 4 * lane);
        a2 += bfpair(u.x) * pj;
        g2 += bfpair(u.y) * wj;
        wsum += wj;
      }
    }
  }
  float inv = linv[(size_t)d * 8 + head];
  float v0 = a2.x * inv, v1 = a2.y * inv;
  v0 = v0 > 0.f ? v0 : __expf(v0) - 1.f;  // ELU
  v1 = v1 > 0.f ? v1 : __expf(v1) - 1.f;
  unsigned xpack = (unsigned)f2bf(v0) | ((unsigned)f2bf(v1) << 16);
  ((unsigned*)x1c)[(size_t)d * 64 + lane] = xpack;
  ((unsigned*)xh)[(size_t)d * 128 + 2 * lane] = xpack;  // x-pair slot of interleaved row
  float ginv = 1.f / fmaxf(wsum, 1e-16f);
  float w0 = fmaxf(g2.x * ginv, 0.f), w1 = fmaxf(g2.y * ginv, 0.f);
  ((unsigned*)x2)[(size_t)d * 64 + lane] = (unsigned)f2bf(w0) | ((unsigned)f2bf(w1) << 16);
}

// =============================== Phase E: layer-1 aggregation (dst-chunked) ==============
// xh row interleaved: 4q,4q+1 = x1 dims 2q,2q+1; 4q+2,4q+3 = h1 dims.
// p precomputed; LDS float4 same-address broadcasts; packed f32x2 accumulation.
__global__ __launch_bounds__(256) void k_agg1(const unsigned short* __restrict__ xh,
                                              const int* __restrict__ rowptr,
                                              const uint2* __restrict__ edata,
                                              const unsigned short* __restrict__ pedge,
                                              const float* __restrict__ linv,
                                              unsigned short* __restrict__ aggbuf,
                                              unsigned short* __restrict__ x2f,
                                              int d0, int d1) {
  __shared__ uint2 swl[4][64];
  __shared__ float pl[4][512];
  int wave = threadIdx.x >> 6, lane = threadIdx.x & 63;
  int d = d0 + blockIdx.x * 4 + wave;
  if (d >= d1) return;
  int beg = rowptr[d], end = rowptr[d + 1], deg = end - beg;
  f32x2 ax2[8] = {};
  f32x2 g2 = {0.f, 0.f};
  float wsum = 0.f;
  for (int base = 0; base < deg; base += 64) {
    int idx = beg + base + lane;
    bool valid = idx < end;
    uint2 sv = make_uint2(0u, 0u);
    float4 pa = {0.f, 0.f, 0.f, 0.f}, pb = {0.f, 0.f, 0.f, 0.f};
    if (valid) {
      sv = edata[idx];
      ushort4 q0 = *(const ushort4*)(pedge + (size_t)idx * 8);
      ushort4 q1 = *(const ushort4*)(pedge + (size_t)idx * 8 + 4);
      pa = make_float4(bflo(q0.x), bflo(q0.y), bflo(q0.z), bflo(q0.w));
      pb = make_float4(bflo(q1.x), bflo(q1.y), bflo(q1.z), bflo(q1.w));
    }
    swl[wave][lane] = sv;
    *(float4*)&pl[wave][lane * 8] = pa;
    *(float4*)&pl[wave][lane * 8 + 4] = pb;
    int ng = deg - base; if (ng > 64) ng = 64;
    int groups = (ng + 7) >> 3;
    for (int g = 0; g < groups; ++g) {
#pragma unroll
      for (int j = 0; j < 8; ++j) {
        int e = g * 8 + j;
        uint2 sw = swl[wave][e];
        float4 pv0 = *(const float4*)&pl[wave][e * 8];
        float4 pv1 = *(const float4*)&pl[wave][e * 8 + 4];
        uint2 u = *(const uint2*)(xh + (size_t)sw.x * 256 + 4 * lane);
        f32x2 xv = bfpair(u.x);
        float wj = __uint_as_float(sw.y);
        g2 += bfpair(u.y) * wj;
        wsum += wj;
        ax2[0] += xv * pv0.x;
        ax2[1] += xv * pv0.y;
        ax2[2] += xv * pv0.z;
        ax2[3] += xv * pv0.w;
        ax2[4] += xv * pv1.x;
        ax2[5] += xv * pv1.y;
        ax2[6] += xv * pv1.z;
        ax2[7] += xv * pv1.w;
      }
    }
  }
  float4 i0 = *(const float4*)(linv + (size_t)d * 8);
  float4 i1 = *(const float4*)(linv + (size_t)d * 8 + 4);
  float invh[8] = {i0.x, i0.y, i0.z, i0.w, i1.x, i1.y, i1.z, i1.w};
  size_t lr = (size_t)(d - d0) * 512;
#pragma unroll
  for (int h = 0; h < 8; ++h) {
    ((unsigned*)aggbuf)[lr + h * 64 + lane] =
        (unsigned)f2bf(ax2[h].x * invh[h]) | ((unsigned)f2bf(ax2[h].y * invh[h]) << 16);
  }
  float ginv = 1.f / fmaxf(wsum, 1e-16f);
  float w0 = fmaxf(g2.x * ginv, 0.f), w1 = fmaxf(g2.y * ginv, 0.f);
  ((unsigned*)x2f)[(size_t)d * 64 + lane] = (unsigned)f2bf(w0) | ((unsigned)f2bf(w1) << 16);
}

// =============================== host launch ===============================

extern "C" void kernel_launch(void* const* d_in, const int* in_sizes, int n_in,
                              void* d_out, int out_size, void* d_ws, size_t ws_size,
                              hipStream_t stream) {
  const float* x   = (const float*)d_in[0];
  const int*   ei  = (const int*)d_in[1];
  const float* ew  = (const float*)d_in[2];
  const float* W0  = (const float*)d_in[3];
  const float* a0s = (const float*)d_in[4];
  const float* a0d = (const float*)d_in[5];
  const float* W1  = (const float*)d_in[6];
  const float* a1s = (const float*)d_in[7];
  const float* a1d = (const float*)d_in[8];
  const float* gw0 = (const float*)d_in[9];
  const float* gw1 = (const float*)d_in[10];
  float* out = (float*)d_out;

  const int N = in_sizes[0] / 128;
  const int E = in_sizes[1] / 2;
  const int* src = ei;
  const int* dst = ei + E;

  // workspace carve (256B aligned); peak ~158 MB (< proven-safe 166 MB)
  char* p = (char*)d_ws;
  auto carve = [&](size_t bytes) {
    void* r = (void*)p;
    p += (bytes + 255) & ~(size_t)255;
    return r;
  };
  int*   cnt    = (int*)carve((size_t)N * 4);
  int*   rowptr = (int*)carve((size_t)(N + 1) * 4);
  int*   cur    = (int*)carve((size_t)N * 4);
  int*   bsum   = (int*)carve(256 * 4);
  uint2* edata  = (uint2*)carve((size_t)E * 8);
  unsigned short* W0catT  = (unsigned short*)carve(32768 * 2);
  float*          logitW  = (float*)carve(2048 * 4);
  unsigned short* gw1T    = (unsigned short*)carve(16384 * 2);
  unsigned short* va1T    = (unsigned short*)carve(2048 * 2);
  unsigned short* WstackT = (unsigned short*)carve(131072 * 2);
  unsigned short* x1c  = (unsigned short*)carve((size_t)N * 128 * 2);
  unsigned short* x2   = (unsigned short*)carve((size_t)N * 128 * 2);
  unsigned short* x2f  = (unsigned short*)carve((size_t)N * 128 * 2);
  float*          esed = (float*)carve((size_t)N * 16 * 4);
  unsigned short* xh   = (unsigned short*)carve((size_t)N * 256 * 2);
  unsigned short* pedge = (unsigned short*)carve((size_t)E * 8 * 2);  // reused layer0/1
  float*          linv0 = (float*)carve((size_t)N * 8 * 4);
  float*          linv1 = (float*)carve((size_t)N * 8 * 4);
  // scratch union: {xb, feat0i, logit0} then reused as aggbuf
  const int CH = 25600;
  size_t ph1 = ((size_t)N * 128 * 2 + 255) & ~(size_t)255;          // xb
  size_t ph2 = ph1 + (((size_t)N * 256 * 2 + 255) & ~(size_t)255);  // +feat0i
  size_t ph3 = ph2 + (((size_t)N * 16 * 4 + 255) & ~(size_t)255);   // +logit0
  size_t scratch_sz = (size_t)CH * 1024 * 2;
  if (ph3 > scratch_sz) scratch_sz = ph3;
  char* scratch = (char*)carve(scratch_sz);
  unsigned short* xb     = (unsigned short*)scratch;
  unsigned short* feat0i = (unsigned short*)(scratch + ph1);
  float*          logit0 = (float*)(scratch + ph2);
  unsigned short* aggbuf = (unsigned short*)scratch;  // alias, live after agg0

  // Phase A: CSR build (single int atomic; no float atomics anywhere)
  hipMemsetAsync(cnt, 0, (size_t)N * 4, stream);
  int gE = (E + 255) / 256;
  k_count<<<gE, 256, 0, stream>>>(dst, cnt, E);
  int nb = (N + 1023) / 1024;
  k_scan1<<<nb, 1024, 0, stream>>>(cnt, rowptr, bsum, N);
  k_scan2<<<1, 64, 0, stream>>>(bsum, rowptr + N, nb);
  k_scan3<<<nb, 1024, 0, stream>>>(rowptr, cur, bsum, N);
  k_scatter<<<gE, 256, 0, stream>>>(src, dst, ew, cur, edata, E);

  // weight packing + fused x-cast/logit0
  k_pack<<<(184320 + 255) / 256, 256, 0, stream>>>(W0, a0s, a0d, W1, a1s, a1d, gw0,
                                                   gw1, W0catT, logitW, gw1T, va1T,
                                                   WstackT);
  k_prep<<<(N + 15) / 16, 256, 0, stream>>>(x, logitW, xb, logit0, N);

  int gM = (N + 63) / 64;
  int gD = (N + 3) / 4;
  // Phase B: feat0i[N,256] bf16 (interleaved cols via W0catT row permutation)
  k_mgemm<8, 1, 0><<<dim3(gM, 2), 256, 0, stream>>>(xb, 128, W0catT, 128, feat0i, 256,
                                                    nullptr, N, 256, 128);
  // layer-0 edge weights, then aggregation
  k_pedge<<<gD, 256, 0, stream>>>(logit0, edata, rowptr, pedge, linv0, N);
  k_agg0<<<gD, 256, 0, stream>>>(feat0i, rowptr, edata, pedge, linv0, x1c, x2, xh, N);

  // Phase D: esed[N,16] fp32 = x1c @ va1T^T ; h1 = x2 @ gw1T^T -> xh interleaved
  k_mgemm<1, 0, 0><<<dim3(gM, 1), 256, 0, stream>>>(x1c, 128, va1T, 128, esed, 16,
                                                    nullptr, N, 16, 128);
  k_mgemm<8, 1, 2><<<dim3(gM, 1), 256, 0, stream>>>(x2, 128, gw1T, 128, xh, 256,
                                                    nullptr, N, 128, 128);

  // layer-1 edge weights (pedge buffer reused)
  k_pedge<<<gD, 256, 0, stream>>>(esed, edata, rowptr, pedge, linv1, N);

  // Phase E/F: dst-chunked layer-1 aggregation + MFMA output GEMM (max-fused, bf16 aux)
  for (int d0 = 0; d0 < N; d0 += CH) {
    int d1 = d0 + CH < N ? d0 + CH : N;
    int chN = d1 - d0;
    k_agg1<<<(chN + 3) / 4, 256, 0, stream>>>(xh, rowptr, edata, pedge, linv1,
                                              aggbuf, x2f, d0, d1);
    k_mgemm<8, 0, 1><<<dim3((chN + 63) / 64, 1), 256, 0, stream>>>(
        aggbuf, 1024, WstackT, 1024, out + (size_t)d0 * 128, 128,
        x2f + (size_t)d0 * 128, chN, 128, 1024);
  }
}

// Round 9
// 492.321 us; speedup vs baseline: 1.0210x; 1.0210x over previous
//
#include <hip/hip_runtime.h>

#define LRELU_ALPHA 0.2f

typedef __attribute__((ext_vector_type(8))) short short8;
typedef __attribute__((ext_vector_type(4))) float float4v;
typedef __attribute__((ext_vector_type(2))) float f32x2;

__device__ __forceinline__ unsigned short f2bf(float f) {
  union { float f; unsigned u; } x; x.f = f;
  unsigned r = (x.u + 0x7fff + ((x.u >> 16) & 1)) >> 16;
  return (unsigned short)r;
}
__device__ __forceinline__ float bflo(unsigned u) {
  union { unsigned u; float f; } x; x.u = u << 16; return x.f;
}
__device__ __forceinline__ float bfhi(unsigned u) {
  union { unsigned u; float f; } x; x.u = u & 0xffff0000u; return x.f;
}
__device__ __forceinline__ f32x2 bfpair(unsigned u) {
  return (f32x2){bflo(u), bfhi(u)};
}
__device__ __forceinline__ unsigned packbf(float a, float b) {
  return (unsigned)f2bf(a) | ((unsigned)f2bf(b) << 16);
}

// =============================== Phase A: CSR build ===============================

__global__ __launch_bounds__(256) void k_count(const int* __restrict__ dst,
                                               int* __restrict__ cnt, int E) {
  int e = blockIdx.x * 256 + threadIdx.x;
  if (e < E) atomicAdd(&cnt[dst[e]], 1);
}

__global__ __launch_bounds__(1024) void k_scan1(const int* __restrict__ cnt,
                                                int* __restrict__ lscan,
                                                int* __restrict__ bsum, int N) {
  __shared__ int sm[1024];
  int t = threadIdx.x;
  int base = blockIdx.x * 1024;
  int v = (base + t < N) ? cnt[base + t] : 0;
  sm[t] = v;
  __syncthreads();
  for (int off = 1; off < 1024; off <<= 1) {
    int x = (t >= off) ? sm[t - off] : 0;
    __syncthreads();
    sm[t] += x;
    __syncthreads();
  }
  if (base + t < N) lscan[base + t] = sm[t] - v;
  if (t == 1023) bsum[blockIdx.x] = sm[1023];
}

// one-wave shfl scan (nb <= 64)
__global__ __launch_bounds__(64) void k_scan2(int* __restrict__ bsum,
                                              int* __restrict__ rowptrN, int nb) {
  int t = threadIdx.x;
  int v = (t < nb) ? bsum[t] : 0;
  int orig = v;
  for (int off = 1; off < 64; off <<= 1) {
    int y = __shfl_up(v, off, 64);
    if (t >= off) v += y;
  }
  if (t < nb) bsum[t] = v - orig;
  if (t == 63) *rowptrN = v;
}

__global__ __launch_bounds__(1024) void k_scan3(int* __restrict__ rowptr,
                                                int* __restrict__ cur,
                                                const int* __restrict__ bsum, int N) {
  int i = blockIdx.x * 1024 + threadIdx.x;
  if (i < N) {
    int v = rowptr[i] + bsum[blockIdx.x];
    rowptr[i] = v;
    cur[i] = v;
  }
}

// scatter + fused layer-0 attention weights (logit0 ready before this launch)
__global__ __launch_bounds__(256) void k_scatter(const int* __restrict__ src,
                                                 const int* __restrict__ dst,
                                                 const float* __restrict__ w,
                                                 const float* __restrict__ logit0,
                                                 int* __restrict__ cur,
                                                 uint2* __restrict__ edata,
                                                 unsigned short* __restrict__ pedge,
                                                 int E) {
  int e = blockIdx.x * 256 + threadIdx.x;
  if (e >= E) return;
  int d = dst[e];
  int s = src[e];
  int p = atomicAdd(&cur[d], 1);
  edata[p] = make_uint2((unsigned)s, __float_as_uint(w[e]));
  float4 es0 = *(const float4*)(logit0 + (size_t)s * 16);
  float4 es1 = *(const float4*)(logit0 + (size_t)s * 16 + 4);
  float4 ed0 = *(const float4*)(logit0 + (size_t)d * 16 + 8);
  float4 ed1 = *(const float4*)(logit0 + (size_t)d * 16 + 12);
  float lg[8] = {es0.x + ed0.x, es0.y + ed0.y, es0.z + ed0.z, es0.w + ed0.w,
                 es1.x + ed1.x, es1.y + ed1.y, es1.z + ed1.z, es1.w + ed1.w};
  unsigned short o[8];
#pragma unroll
  for (int h = 0; h < 8; ++h) {
    float v = lg[h] > 0.f ? lg[h] : LRELU_ALPHA * lg[h];
    o[h] = f2bf(__expf(fminf(v, 80.f)));
  }
  ushort4 q0 = {o[0], o[1], o[2], o[3]};
  ushort4 q1 = {o[4], o[5], o[6], o[7]};
  *(ushort4*)(pedge + (size_t)p * 8) = q0;
  *(ushort4*)(pedge + (size_t)p * 8 + 4) = q1;
}

// =============================== weight packing ===============================
// W0catT bf16 [256][128], ROW-PERMUTED for interleaved feat0i:
//   row n: q=n>>2, r=n&3. r<2 -> GAT col o=2q+r (h=o>>4,f=o&15): W0[h,k,f]
//                        r>=2 -> GCN col j=2q+(r-2): gcn_W0[k][j]
// logitW  fp32 [128][16] : c<8: va0_src[k][h=c]; c>=8: va0_dst[k][h=c-8]
// gw1T    bf16 [128][128]: gw1T[n][k] = gcn_W1[k][n]
// va1T    bf16 [16][128] : c<8: W1[h=c]@a1_src; c>=8: W1[h]@a1_dst
// WstackT bf16 [128][1024]: WstackT[n][h*128+k] = W1[h][k][n] * 0.125
__global__ __launch_bounds__(256) void k_pack(const float* __restrict__ W0,
                                              const float* __restrict__ a0s,
                                              const float* __restrict__ a0d,
                                              const float* __restrict__ W1,
                                              const float* __restrict__ a1s,
                                              const float* __restrict__ a1d,
                                              const float* __restrict__ gw0,
                                              const float* __restrict__ gw1,
                                              unsigned short* __restrict__ W0catT,
                                              float* __restrict__ logitW,
                                              unsigned short* __restrict__ gw1T,
                                              unsigned short* __restrict__ va1T,
                                              unsigned short* __restrict__ WstackT) {
  int idx = blockIdx.x * 256 + threadIdx.x;
  if (idx < 32768) {
    int n = idx >> 7, k = idx & 127;
    int q = n >> 2, r = n & 3;
    float v;
    if (r < 2) {
      int o = 2 * q + r;
      int h = o >> 4, f = o & 15;
      v = W0[h * 2048 + k * 16 + f];
    } else {
      int j = 2 * q + (r - 2);
      v = gw0[k * 128 + j];
    }
    W0catT[idx] = f2bf(v);
  } else if (idx < 34816) {
    int j = idx - 32768;
    int k = j >> 4, c = j & 15;
    int h = (c < 8) ? c : c - 8;
    const float* a = (c < 8) ? a0s : a0d;
    float s = 0.f;
    for (int f = 0; f < 16; ++f) s += W0[h * 2048 + k * 16 + f] * a[h * 16 + f];
    logitW[j] = s;
  } else if (idx < 51200) {
    int j = idx - 34816;
    int n = j >> 7, k = j & 127;
    gw1T[j] = f2bf(gw1[k * 128 + n]);
  } else if (idx < 53248) {
    int j = idx - 51200;
    int c = j >> 7, k = j & 127;
    int h = c & 7;
    const float* a = (c < 8) ? a1s : a1d;
    float s = 0.f;
    for (int f = 0; f < 128; ++f) s += W1[h * 16384 + k * 128 + f] * a[h * 128 + f];
    va1T[j] = f2bf(s);
  } else if (idx < 184320) {
    int j = idx - 53248;
    int n = j >> 10, kk = j & 1023;
    int h = kk >> 7, k = kk & 127;
    WstackT[j] = f2bf(W1[h * 16384 + k * 128 + n] * 0.125f);
  }
}

// fused: xb = bf16(x), logit0[N,16] = x @ logitW; 16 rows per block
__global__ __launch_bounds__(256) void k_prep(const float* __restrict__ x,
                                              const float* __restrict__ logitW,
                                              unsigned short* __restrict__ xb,
                                              float* __restrict__ logit0, int N) {
  __shared__ float sm[16][132];
  __shared__ float sw[2048];
  int t = threadIdx.x;
  int base = blockIdx.x * 16;
  int r = t >> 4, cc = (t & 15) * 8;
  const float* xr = x + (size_t)(base + r) * 128 + cc;
  float4 v0 = *(const float4*)xr;
  float4 v1 = *(const float4*)(xr + 4);
  ushort4 o0 = {f2bf(v0.x), f2bf(v0.y), f2bf(v0.z), f2bf(v0.w)};
  ushort4 o1 = {f2bf(v1.x), f2bf(v1.y), f2bf(v1.z), f2bf(v1.w)};
  *(ushort4*)(xb + (size_t)(base + r) * 128 + cc) = o0;
  *(ushort4*)(xb + (size_t)(base + r) * 128 + cc + 4) = o1;
  *(float4*)&sm[r][cc] = v0;
  *(float4*)&sm[r][cc + 4] = v1;
  *(float4*)&sw[t * 8] = *(const float4*)(logitW + t * 8);
  *(float4*)&sw[t * 8 + 4] = *(const float4*)(logitW + t * 8 + 4);
  __syncthreads();
  int c = t & 15;
  float acc = 0.f;
#pragma unroll
  for (int k = 0; k < 128; ++k) acc += sm[r][k] * sw[k * 16 + c];
  logit0[(size_t)(base + r) * 16 + c] = acc;
}

// =============================== edge-weight precompute (layer 1) ===============================
__global__ __launch_bounds__(256) void k_pedge(const float* __restrict__ logits,
                                               const uint2* __restrict__ edata,
                                               const int* __restrict__ rowptr,
                                               unsigned short* __restrict__ pedge,
                                               float* __restrict__ linv, int N) {
  int wave = threadIdx.x >> 6, lane = threadIdx.x & 63;
  int d = blockIdx.x * 4 + wave;
  if (d >= N) return;
  int j8 = lane >> 3, h = lane & 7;
  float edv = logits[(size_t)d * 16 + 8 + h];
  int beg = rowptr[d], end = rowptr[d + 1];
  float lsum = 0.f;
  for (int ii = beg + j8; ii < end; ii += 8) {
    unsigned s = edata[ii].x;
    float es = logits[(size_t)s * 16 + h];
    float lg = es + edv;
    lg = lg > 0.f ? lg : LRELU_ALPHA * lg;
    float p = __expf(fminf(lg, 80.f));
    lsum += p;
    pedge[(size_t)ii * 8 + h] = f2bf(p);
  }
  lsum += __shfl_xor(lsum, 8, 64);
  lsum += __shfl_xor(lsum, 16, 64);
  lsum += __shfl_xor(lsum, 32, 64);
  if (lane < 8) linv[(size_t)d * 8 + h] = lsum > 0.f ? 1.f / lsum : 0.f;
}

// =============================== bf16 MFMA GEMM ===============================
// C = A[M,K] @ BT[Ncols,K]^T. EPI: 0 plain, 1 max(acc, bf16 aux), 2 interleaved-xh write
template <int NT, int OUT_BF16, int EPI>
__global__ __launch_bounds__(256) void k_mgemm(const unsigned short* __restrict__ A, int lda,
                                               const unsigned short* __restrict__ BT, int ldb,
                                               void* __restrict__ Cv, int ldc,
                                               const void* __restrict__ aux,
                                               int M, int Ncols, int K) {
  __shared__ unsigned short As[64][64];
  __shared__ unsigned short Bs[NT * 16][64];
  int tid = threadIdx.x;
  int w = tid >> 6, lane = tid & 63;
  int quad = lane >> 4, l16 = lane & 15;
  int row0 = blockIdx.x * 64;
  int c0 = blockIdx.y * (NT * 16);
  float4v acc[NT];
#pragma unroll
  for (int t = 0; t < NT; ++t) acc[t] = (float4v){0.f, 0.f, 0.f, 0.f};

  for (int k0 = 0; k0 < K; k0 += 64) {
    __syncthreads();
#pragma unroll
    for (int i = 0; i < 2; ++i) {
      int c = tid + i * 256;
      int r = c >> 3, kc = c & 7;
      uint4 v = {0u, 0u, 0u, 0u};
      int gr = row0 + r;
      if (gr < M) v = *(const uint4*)(A + (size_t)gr * lda + k0 + kc * 8);
      *(uint4*)(&As[r][(kc ^ (r & 7)) * 8]) = v;
    }
#pragma unroll
    for (int i = 0; i < (NT * 128 + 255) / 256; ++i) {
      int c = tid + i * 256;
      if (c < NT * 128) {
        int n = c >> 3, kc = c & 7;
        uint4 v = {0u, 0u, 0u, 0u};
        int gn = c0 + n;
        if (gn < Ncols) v = *(const uint4*)(BT + (size_t)gn * ldb + k0 + kc * 8);
        *(uint4*)(&Bs[n][(kc ^ (n & 7)) * 8]) = v;
      }
    }
    __syncthreads();
#pragma unroll
    for (int ks = 0; ks < 2; ++ks) {
      int m = w * 16 + l16;
      int ga = (ks * 4 + quad) ^ (m & 7);
      short8 a = *(const short8*)(&As[m][ga * 8]);
#pragma unroll
      for (int t = 0; t < NT; ++t) {
        int n = t * 16 + l16;
        int gb = (ks * 4 + quad) ^ (n & 7);
        short8 b = *(const short8*)(&Bs[n][gb * 8]);
        acc[t] = __builtin_amdgcn_mfma_f32_16x16x32_bf16(a, b, acc[t], 0, 0, 0);
      }
    }
  }
#pragma unroll
  for (int t = 0; t < NT; ++t) {
    int cc = c0 + t * 16 + l16;
    if (cc >= Ncols) continue;
#pragma unroll
    for (int i = 0; i < 4; ++i) {
      int rr = row0 + w * 16 + quad * 4 + i;
      if (rr >= M) continue;
      float v = acc[t][i];
      if (EPI == 1) {
        unsigned short us = ((const unsigned short*)aux)[(size_t)rr * ldc + cc];
        v = fmaxf(v, bflo((unsigned)us));
      }
      if (EPI == 2) {
        // h1 -> xh interleaved: col cc -> 4*(cc>>1) + 2 + (cc&1)
        ((unsigned short*)Cv)[(size_t)rr * 256 + 4 * (cc >> 1) + 2 + (cc & 1)] = f2bf(v);
      } else if (OUT_BF16)
        ((unsigned short*)Cv)[(size_t)rr * ldc + cc] = f2bf(v);
      else
        ((float*)Cv)[(size_t)rr * ldc + cc] = v;
    }
  }
}

// =============================== Phase C: layer-0 aggregation ===============================
// HALF-WAVE scheme: lane2=lane&31 covers 4 GAT dims + 4 GCN dims (uint4/row);
// half=lane>>5 processes alternate edges. Softmax denom computed inline from staged p.
__global__ __launch_bounds__(256) void k_agg0(const unsigned short* __restrict__ feat0i,
                                              const int* __restrict__ rowptr,
                                              const uint2* __restrict__ edata,
                                              const unsigned short* __restrict__ pedge,
                                              unsigned short* __restrict__ x1c,
                                              unsigned short* __restrict__ x2,
                                              unsigned short* __restrict__ xh, int N) {
  __shared__ uint2 swl[4][64];
  __shared__ float pl[4][512];
  int wave = threadIdx.x >> 6, lane = threadIdx.x & 63;
  int d = blockIdx.x * 4 + wave;
  if (d >= N) return;
  int half = lane >> 5, lane2 = lane & 31;
  int head = lane2 >> 2;
  int beg = rowptr[d], end = rowptr[d + 1], deg = end - beg;
  f32x2 aa = {0.f, 0.f}, ab = {0.f, 0.f}, ga = {0.f, 0.f}, gb = {0.f, 0.f};
  float l = 0.f, wsum = 0.f;
  for (int base = 0; base < deg; base += 64) {
    int idx = beg + base + lane;
    uint2 sv = make_uint2(0u, 0u);
    uint4 q = make_uint4(0u, 0u, 0u, 0u);
    if (idx < end) {
      sv = edata[idx];
      q = *(const uint4*)(pedge + (size_t)idx * 8);
    }
    swl[wave][lane] = sv;
    float4 pa = make_float4(bflo(q.x), bfhi(q.x), bflo(q.y), bfhi(q.y));
    float4 pb = make_float4(bflo(q.z), bfhi(q.z), bflo(q.w), bfhi(q.w));
    *(float4*)&pl[wave][lane * 8] = pa;
    *(float4*)&pl[wave][lane * 8 + 4] = pb;
    int ng = deg - base; if (ng > 64) ng = 64;
    int tp = (ng + 1) >> 1;
    for (int t = 0; t < tp; ++t) {
      int e = 2 * t + half;
      uint2 sw = swl[wave][e];
      float p = pl[wave][e * 8 + head];
      float wj = __uint_as_float(sw.y);
      uint4 u = *(const uint4*)(feat0i + (size_t)sw.x * 256 + 8 * lane2);
      aa += bfpair(u.x) * p;
      ga += bfpair(u.y) * wj;
      ab += bfpair(u.z) * p;
      gb += bfpair(u.w) * wj;
      l += p;
      wsum += wj;
    }
  }
  // combine halves
  aa.x += __shfl_xor(aa.x, 32, 64); aa.y += __shfl_xor(aa.y, 32, 64);
  ab.x += __shfl_xor(ab.x, 32, 64); ab.y += __shfl_xor(ab.y, 32, 64);
  ga.x += __shfl_xor(ga.x, 32, 64); ga.y += __shfl_xor(ga.y, 32, 64);
  gb.x += __shfl_xor(gb.x, 32, 64); gb.y += __shfl_xor(gb.y, 32, 64);
  l += __shfl_xor(l, 32, 64);
  wsum += __shfl_xor(wsum, 32, 64);
  if (half == 0) {
    float inv = l > 0.f ? 1.f / l : 0.f;
    float v0 = aa.x * inv, v1 = aa.y * inv, v2 = ab.x * inv, v3 = ab.y * inv;
    v0 = v0 > 0.f ? v0 : __expf(v0) - 1.f;  // ELU
    v1 = v1 > 0.f ? v1 : __expf(v1) - 1.f;
    v2 = v2 > 0.f ? v2 : __expf(v2) - 1.f;
    v3 = v3 > 0.f ? v3 : __expf(v3) - 1.f;
    unsigned p0 = packbf(v0, v1), p1 = packbf(v2, v3);
    ((uint2*)x1c)[(size_t)d * 32 + lane2] = make_uint2(p0, p1);
    ((unsigned*)xh)[(size_t)d * 128 + 4 * lane2] = p0;      // x-pair q=2*lane2
    ((unsigned*)xh)[(size_t)d * 128 + 4 * lane2 + 2] = p1;  // x-pair q+1
    float ginv = 1.f / fmaxf(wsum, 1e-16f);
    float w0 = fmaxf(ga.x * ginv, 0.f), w1 = fmaxf(ga.y * ginv, 0.f);
    float w2 = fmaxf(gb.x * ginv, 0.f), w3 = fmaxf(gb.y * ginv, 0.f);
    ((uint2*)x2)[(size_t)d * 32 + lane2] = make_uint2(packbf(w0, w1), packbf(w2, w3));
  }
}

// =============================== Phase E: layer-1 aggregation (dst-chunked) ==============
// HALF-WAVE: lane2 covers x-pairs q=2*lane2, 2*lane2+1 (+h1 pairs); halves alternate edges.
__global__ __launch_bounds__(256) void k_agg1(const unsigned short* __restrict__ xh,
                                              const int* __restrict__ rowptr,
                                              const uint2* __restrict__ edata,
                                              const unsigned short* __restrict__ pedge,
                                              const float* __restrict__ linv,
                                              unsigned short* __restrict__ aggbuf,
                                              unsigned short* __restrict__ x2f,
                                              int d0, int d1) {
  __shared__ uint2 swl[4][64];
  __shared__ float pl[4][512];
  int wave = threadIdx.x >> 6, lane = threadIdx.x & 63;
  int d = d0 + blockIdx.x * 4 + wave;
  if (d >= d1) return;
  int half = lane >> 5, lane2 = lane & 31;
  int beg = rowptr[d], end = rowptr[d + 1], deg = end - beg;
  f32x2 axA[8] = {}, axB[8] = {};
  f32x2 ga = {0.f, 0.f}, gb = {0.f, 0.f};
  float wsum = 0.f;
  for (int base = 0; base < deg; base += 64) {
    int idx = beg + base + lane;
    uint2 sv = make_uint2(0u, 0u);
    uint4 q = make_uint4(0u, 0u, 0u, 0u);
    if (idx < end) {
      sv = edata[idx];
      q = *(const uint4*)(pedge + (size_t)idx * 8);
    }
    swl[wave][lane] = sv;
    float4 pa = make_float4(bflo(q.x), bfhi(q.x), bflo(q.y), bfhi(q.y));
    float4 pb = make_float4(bflo(q.z), bfhi(q.z), bflo(q.w), bfhi(q.w));
    *(float4*)&pl[wave][lane * 8] = pa;
    *(float4*)&pl[wave][lane * 8 + 4] = pb;
    int ng = deg - base; if (ng > 64) ng = 64;
    int tp = (ng + 1) >> 1;
    for (int t = 0; t < tp; ++t) {
      int e = 2 * t + half;
      uint2 sw = swl[wave][e];
      float4 pv0 = *(const float4*)&pl[wave][e * 8];
      float4 pv1 = *(const float4*)&pl[wave][e * 8 + 4];
      float wj = __uint_as_float(sw.y);
      uint4 u = *(const uint4*)(xh + (size_t)sw.x * 256 + 8 * lane2);
      f32x2 xA = bfpair(u.x), hA = bfpair(u.y);
      f32x2 xB = bfpair(u.z), hB = bfpair(u.w);
      ga += hA * wj;
      gb += hB * wj;
      wsum += wj;
      axA[0] += xA * pv0.x; axB[0] += xB * pv0.x;
      axA[1] += xA * pv0.y; axB[1] += xB * pv0.y;
      axA[2] += xA * pv0.z; axB[2] += xB * pv0.z;
      axA[3] += xA * pv0.w; axB[3] += xB * pv0.w;
      axA[4] += xA * pv1.x; axB[4] += xB * pv1.x;
      axA[5] += xA * pv1.y; axB[5] += xB * pv1.y;
      axA[6] += xA * pv1.z; axB[6] += xB * pv1.z;
      axA[7] += xA * pv1.w; axB[7] += xB * pv1.w;
    }
  }
  // combine halves
#pragma unroll
  for (int h = 0; h < 8; ++h) {
    axA[h].x += __shfl_xor(axA[h].x, 32, 64); axA[h].y += __shfl_xor(axA[h].y, 32, 64);
    axB[h].x += __shfl_xor(axB[h].x, 32, 64); axB[h].y += __shfl_xor(axB[h].y, 32, 64);
  }
  ga.x += __shfl_xor(ga.x, 32, 64); ga.y += __shfl_xor(ga.y, 32, 64);
  gb.x += __shfl_xor(gb.x, 32, 64); gb.y += __shfl_xor(gb.y, 32, 64);
  wsum += __shfl_xor(wsum, 32, 64);
  if (half == 0) {
    float4 i0 = *(const float4*)(linv + (size_t)d * 8);
    float4 i1 = *(const float4*)(linv + (size_t)d * 8 + 4);
    float invh[8] = {i0.x, i0.y, i0.z, i0.w, i1.x, i1.y, i1.z, i1.w};
    size_t lr2 = (size_t)(d - d0) * 256;  // uint2 units
#pragma unroll
    for (int h = 0; h < 8; ++h) {
      ((uint2*)aggbuf)[lr2 + h * 32 + lane2] =
          make_uint2(packbf(axA[h].x * invh[h], axA[h].y * invh[h]),
                     packbf(axB[h].x * invh[h], axB[h].y * invh[h]));
    }
    float ginv = 1.f / fmaxf(wsum, 1e-16f);
    float w0 = fmaxf(ga.x * ginv, 0.f), w1 = fmaxf(ga.y * ginv, 0.f);
    float w2 = fmaxf(gb.x * ginv, 0.f), w3 = fmaxf(gb.y * ginv, 0.f);
    ((uint2*)x2f)[(size_t)d * 32 + lane2] = make_uint2(packbf(w0, w1), packbf(w2, w3));
  }
}

// =============================== host launch ===============================

extern "C" void kernel_launch(void* const* d_in, const int* in_sizes, int n_in,
                              void* d_out, int out_size, void* d_ws, size_t ws_size,
                              hipStream_t stream) {
  const float* x   = (const float*)d_in[0];
  const int*   ei  = (const int*)d_in[1];
  const float* ew  = (const float*)d_in[2];
  const float* W0  = (const float*)d_in[3];
  const float* a0s = (const float*)d_in[4];
  const float* a0d = (const float*)d_in[5];
  const float* W1  = (const float*)d_in[6];
  const float* a1s = (const float*)d_in[7];
  const float* a1d = (const float*)d_in[8];
  const float* gw0 = (const float*)d_in[9];
  const float* gw1 = (const float*)d_in[10];
  float* out = (float*)d_out;

  const int N = in_sizes[0] / 128;
  const int E = in_sizes[1] / 2;
  const int* src = ei;
  const int* dst = ei + E;

  // workspace carve (256B aligned); peak ~141 MB (< proven-safe 166 MB)
  char* p = (char*)d_ws;
  auto carve = [&](size_t bytes) {
    void* r = (void*)p;
    p += (bytes + 255) & ~(size_t)255;
    return r;
  };
  int*   cnt    = (int*)carve((size_t)N * 4);
  int*   rowptr = (int*)carve((size_t)(N + 1) * 4);
  int*   cur    = (int*)carve((size_t)N * 4);
  int*   bsum   = (int*)carve(256 * 4);
  uint2* edata  = (uint2*)carve((size_t)E * 8);
  unsigned short* W0catT  = (unsigned short*)carve(32768 * 2);
  float*          logitW  = (float*)carve(2048 * 4);
  unsigned short* gw1T    = (unsigned short*)carve(16384 * 2);
  unsigned short* va1T    = (unsigned short*)carve(2048 * 2);
  unsigned short* WstackT = (unsigned short*)carve(131072 * 2);
  unsigned short* x1c  = (unsigned short*)carve((size_t)N * 128 * 2);
  unsigned short* x2   = (unsigned short*)carve((size_t)N * 128 * 2);
  unsigned short* x2f  = (unsigned short*)carve((size_t)N * 128 * 2);
  float*          esed = (float*)carve((size_t)N * 16 * 4);
  unsigned short* xh   = (unsigned short*)carve((size_t)N * 256 * 2);
  unsigned short* pedge = (unsigned short*)carve((size_t)E * 8 * 2);  // layer0 then layer1
  float*          linv1 = (float*)carve((size_t)N * 8 * 4);
  // scratch union: {xb, feat0i, logit0} then reused as aggbuf
  const int CH = 25600;
  size_t ph1 = ((size_t)N * 128 * 2 + 255) & ~(size_t)255;          // xb
  size_t ph2 = ph1 + (((size_t)N * 256 * 2 + 255) & ~(size_t)255);  // +feat0i
  size_t ph3 = ph2 + (((size_t)N * 16 * 4 + 255) & ~(size_t)255);   // +logit0
  size_t scratch_sz = (size_t)CH * 1024 * 2;
  if (ph3 > scratch_sz) scratch_sz = ph3;
  char* scratch = (char*)carve(scratch_sz);
  unsigned short* xb     = (unsigned short*)scratch;
  unsigned short* feat0i = (unsigned short*)(scratch + ph1);
  float*          logit0 = (float*)(scratch + ph2);
  unsigned short* aggbuf = (unsigned short*)scratch;  // alias, live after agg0

  int gE = (E + 255) / 256;
  int nb = (N + 1023) / 1024;
  int gM = (N + 63) / 64;
  int gD = (N + 3) / 4;

  // Phase A1: counts + scan (independent of weights)
  hipMemsetAsync(cnt, 0, (size_t)N * 4, stream);
  k_count<<<gE, 256, 0, stream>>>(dst, cnt, E);
  k_scan1<<<nb, 1024, 0, stream>>>(cnt, rowptr, bsum, N);
  k_scan2<<<1, 64, 0, stream>>>(bsum, rowptr + N, nb);
  k_scan3<<<nb, 1024, 0, stream>>>(rowptr, cur, bsum, N);

  // weight packing + fused x-cast/logit0 (before scatter: scatter consumes logit0)
  k_pack<<<(184320 + 255) / 256, 256, 0, stream>>>(W0, a0s, a0d, W1, a1s, a1d, gw0,
                                                   gw1, W0catT, logitW, gw1T, va1T,
                                                   WstackT);
  k_prep<<<(N + 15) / 16, 256, 0, stream>>>(x, logitW, xb, logit0, N);

  // Phase A2: scatter + fused layer-0 attention weights
  k_scatter<<<gE, 256, 0, stream>>>(src, dst, ew, logit0, cur, edata, pedge, E);

  // Phase B: feat0i[N,256] bf16 (interleaved cols via W0catT row permutation)
  k_mgemm<8, 1, 0><<<dim3(gM, 2), 256, 0, stream>>>(xb, 128, W0catT, 128, feat0i, 256,
                                                    nullptr, N, 256, 128);
  // Phase C: layer-0 GAT softmax-agg + ELU -> x1c & xh ; GCN agg + ReLU -> x2
  k_agg0<<<gD, 256, 0, stream>>>(feat0i, rowptr, edata, pedge, x1c, x2, xh, N);

  // Phase D: esed[N,16] fp32 = x1c @ va1T^T ; h1 = x2 @ gw1T^T -> xh interleaved
  k_mgemm<1, 0, 0><<<dim3(gM, 1), 256, 0, stream>>>(x1c, 128, va1T, 128, esed, 16,
                                                    nullptr, N, 16, 128);
  k_mgemm<8, 1, 2><<<dim3(gM, 1), 256, 0, stream>>>(x2, 128, gw1T, 128, xh, 256,
                                                    nullptr, N, 128, 128);

  // layer-1 edge weights (pedge buffer reused)
  k_pedge<<<gD, 256, 0, stream>>>(esed, edata, rowptr, pedge, linv1, N);

  // Phase E/F: dst-chunked layer-1 aggregation + MFMA output GEMM (max-fused, bf16 aux)
  for (int d0 = 0; d0 < N; d0 += CH) {
    int d1 = d0 + CH < N ? d0 + CH : N;
    int chN = d1 - d0;
    k_agg1<<<(chN + 3) / 4, 256, 0, stream>>>(xh, rowptr, edata, pedge, linv1,
                                              aggbuf, x2f, d0, d1);
    k_mgemm<8, 0, 1><<<dim3((chN + 63) / 64, 1), 256, 0, stream>>>(
        aggbuf, 1024, WstackT, 1024, out + (size_t)d0 * 128, 128,
        x2f + (size_t)d0 * 128, chN, 128, 1024);
  }
}

// Round 10
// 464.062 us; speedup vs baseline: 1.0832x; 1.0609x over previous
//
#include <hip/hip_runtime.h>

#define LRELU_ALPHA 0.2f

typedef __attribute__((ext_vector_type(8))) short short8;
typedef __attribute__((ext_vector_type(4))) float float4v;
typedef __attribute__((ext_vector_type(2))) float f32x2;

__device__ __forceinline__ unsigned short f2bf(float f) {
  union { float f; unsigned u; } x; x.f = f;
  unsigned r = (x.u + 0x7fff + ((x.u >> 16) & 1)) >> 16;
  return (unsigned short)r;
}
__device__ __forceinline__ float bflo(unsigned u) {
  union { unsigned u; float f; } x; x.u = u << 16; return x.f;
}
__device__ __forceinline__ float bfhi(unsigned u) {
  union { unsigned u; float f; } x; x.u = u & 0xffff0000u; return x.f;
}
__device__ __forceinline__ f32x2 bfpair(unsigned u) {
  return (f32x2){bflo(u), bfhi(u)};
}
__device__ __forceinline__ unsigned packbf(float a, float b) {
  return (unsigned)f2bf(a) | ((unsigned)f2bf(b) << 16);
}

// =============================== Phase A: CSR build ===============================

__global__ __launch_bounds__(256) void k_count(const int* __restrict__ dst,
                                               int* __restrict__ cnt, int E) {
  int e = blockIdx.x * 256 + threadIdx.x;
  if (e < E) atomicAdd(&cnt[dst[e]], 1);
}

__global__ __launch_bounds__(1024) void k_scan1(const int* __restrict__ cnt,
                                                int* __restrict__ lscan,
                                                int* __restrict__ bsum, int N) {
  __shared__ int sm[1024];
  int t = threadIdx.x;
  int base = blockIdx.x * 1024;
  int v = (base + t < N) ? cnt[base + t] : 0;
  sm[t] = v;
  __syncthreads();
  for (int off = 1; off < 1024; off <<= 1) {
    int x = (t >= off) ? sm[t - off] : 0;
    __syncthreads();
    sm[t] += x;
    __syncthreads();
  }
  if (base + t < N) lscan[base + t] = sm[t] - v;
  if (t == 1023) bsum[blockIdx.x] = sm[1023];
}

// one-wave shfl scan (nb <= 64)
__global__ __launch_bounds__(64) void k_scan2(int* __restrict__ bsum,
                                              int* __restrict__ rowptrN, int nb) {
  int t = threadIdx.x;
  int v = (t < nb) ? bsum[t] : 0;
  int orig = v;
  for (int off = 1; off < 64; off <<= 1) {
    int y = __shfl_up(v, off, 64);
    if (t >= off) v += y;
  }
  if (t < nb) bsum[t] = v - orig;
  if (t == 63) *rowptrN = v;
}

__global__ __launch_bounds__(1024) void k_scan3(int* __restrict__ rowptr,
                                                int* __restrict__ cur,
                                                const int* __restrict__ bsum, int N) {
  int i = blockIdx.x * 1024 + threadIdx.x;
  if (i < N) {
    int v = rowptr[i] + bsum[blockIdx.x];
    rowptr[i] = v;
    cur[i] = v;
  }
}

// scatter + fused layer-0 attention weights (logit0 ready before this launch)
__global__ __launch_bounds__(256) void k_scatter(const int* __restrict__ src,
                                                 const int* __restrict__ dst,
                                                 const float* __restrict__ w,
                                                 const float* __restrict__ logit0,
                                                 int* __restrict__ cur,
                                                 uint2* __restrict__ edata,
                                                 unsigned short* __restrict__ pedge,
                                                 int E) {
  int e = blockIdx.x * 256 + threadIdx.x;
  if (e >= E) return;
  int d = dst[e];
  int s = src[e];
  int p = atomicAdd(&cur[d], 1);
  edata[p] = make_uint2((unsigned)s, __float_as_uint(w[e]));
  float4 es0 = *(const float4*)(logit0 + (size_t)s * 16);
  float4 es1 = *(const float4*)(logit0 + (size_t)s * 16 + 4);
  float4 ed0 = *(const float4*)(logit0 + (size_t)d * 16 + 8);
  float4 ed1 = *(const float4*)(logit0 + (size_t)d * 16 + 12);
  float lg[8] = {es0.x + ed0.x, es0.y + ed0.y, es0.z + ed0.z, es0.w + ed0.w,
                 es1.x + ed1.x, es1.y + ed1.y, es1.z + ed1.z, es1.w + ed1.w};
  unsigned short o[8];
#pragma unroll
  for (int h = 0; h < 8; ++h) {
    float v = lg[h] > 0.f ? lg[h] : LRELU_ALPHA * lg[h];
    o[h] = f2bf(__expf(fminf(v, 80.f)));
  }
  ushort4 q0 = {o[0], o[1], o[2], o[3]};
  ushort4 q1 = {o[4], o[5], o[6], o[7]};
  *(ushort4*)(pedge + (size_t)p * 8) = q0;
  *(ushort4*)(pedge + (size_t)p * 8 + 4) = q1;
}

// =============================== weight packing ===============================
// W0catT bf16 [256][128], ROW-PERMUTED for interleaved feat0:
//   row n: q=n>>2, r=n&3. r<2 -> GAT col o=2q+r (h=o>>4,f=o&15): W0[h,k,f]
//                        r>=2 -> GCN col j=2q+(r-2): gcn_W0[k][j]
// logitW  fp32 [128][16] : c<8: va0_src[k][h=c]; c>=8: va0_dst[k][h=c-8]
// gw1T    bf16 [128][128]: gw1T[n][k] = gcn_W1[k][n]
// va1T    bf16 [16][128] : c<8: W1[h=c]@a1_src; c>=8: W1[h]@a1_dst
// WstackT bf16 [128][1024]: WstackT[n][h*128+k] = W1[h][k][n] * 0.125
__global__ __launch_bounds__(256) void k_pack(const float* __restrict__ W0,
                                              const float* __restrict__ a0s,
                                              const float* __restrict__ a0d,
                                              const float* __restrict__ W1,
                                              const float* __restrict__ a1s,
                                              const float* __restrict__ a1d,
                                              const float* __restrict__ gw0,
                                              const float* __restrict__ gw1,
                                              unsigned short* __restrict__ W0catT,
                                              float* __restrict__ logitW,
                                              unsigned short* __restrict__ gw1T,
                                              unsigned short* __restrict__ va1T,
                                              unsigned short* __restrict__ WstackT) {
  int idx = blockIdx.x * 256 + threadIdx.x;
  if (idx < 32768) {
    int n = idx >> 7, k = idx & 127;
    int q = n >> 2, r = n & 3;
    float v;
    if (r < 2) {
      int o = 2 * q + r;
      int h = o >> 4, f = o & 15;
      v = W0[h * 2048 + k * 16 + f];
    } else {
      int j = 2 * q + (r - 2);
      v = gw0[k * 128 + j];
    }
    W0catT[idx] = f2bf(v);
  } else if (idx < 34816) {
    int j = idx - 32768;
    int k = j >> 4, c = j & 15;
    int h = (c < 8) ? c : c - 8;
    const float* a = (c < 8) ? a0s : a0d;
    float s = 0.f;
    for (int f = 0; f < 16; ++f) s += W0[h * 2048 + k * 16 + f] * a[h * 16 + f];
    logitW[j] = s;
  } else if (idx < 51200) {
    int j = idx - 34816;
    int n = j >> 7, k = j & 127;
    gw1T[j] = f2bf(gw1[k * 128 + n]);
  } else if (idx < 53248) {
    int j = idx - 51200;
    int c = j >> 7, k = j & 127;
    int h = c & 7;
    const float* a = (c < 8) ? a1s : a1d;
    float s = 0.f;
    for (int f = 0; f < 128; ++f) s += W1[h * 16384 + k * 128 + f] * a[h * 128 + f];
    va1T[j] = f2bf(s);
  } else if (idx < 184320) {
    int j = idx - 53248;
    int n = j >> 10, kk = j & 1023;
    int h = kk >> 7, k = kk & 127;
    WstackT[j] = f2bf(W1[h * 16384 + k * 128 + n] * 0.125f);
  }
}

// fused: xb = bf16(x), logit0[N,16] = x @ logitW; 16 rows per block
__global__ __launch_bounds__(256) void k_prep(const float* __restrict__ x,
                                              const float* __restrict__ logitW,
                                              unsigned short* __restrict__ xb,
                                              float* __restrict__ logit0, int N) {
  __shared__ float sm[16][132];
  __shared__ float sw[2048];
  int t = threadIdx.x;
  int base = blockIdx.x * 16;
  int r = t >> 4, cc = (t & 15) * 8;
  const float* xr = x + (size_t)(base + r) * 128 + cc;
  float4 v0 = *(const float4*)xr;
  float4 v1 = *(const float4*)(xr + 4);
  ushort4 o0 = {f2bf(v0.x), f2bf(v0.y), f2bf(v0.z), f2bf(v0.w)};
  ushort4 o1 = {f2bf(v1.x), f2bf(v1.y), f2bf(v1.z), f2bf(v1.w)};
  *(ushort4*)(xb + (size_t)(base + r) * 128 + cc) = o0;
  *(ushort4*)(xb + (size_t)(base + r) * 128 + cc + 4) = o1;
  *(float4*)&sm[r][cc] = v0;
  *(float4*)&sm[r][cc + 4] = v1;
  *(float4*)&sw[t * 8] = *(const float4*)(logitW + t * 8);
  *(float4*)&sw[t * 8 + 4] = *(const float4*)(logitW + t * 8 + 4);
  __syncthreads();
  int c = t & 15;
  float acc = 0.f;
#pragma unroll
  for (int k = 0; k < 128; ++k) acc += sm[r][k] * sw[k * 16 + c];
  logit0[(size_t)(base + r) * 16 + c] = acc;
}

// =============================== edge-weight precompute (layer 1) ===============================
__global__ __launch_bounds__(256) void k_pedge(const float* __restrict__ logits,
                                               const uint2* __restrict__ edata,
                                               const int* __restrict__ rowptr,
                                               unsigned short* __restrict__ pedge,
                                               float* __restrict__ linv, int N) {
  int wave = threadIdx.x >> 6, lane = threadIdx.x & 63;
  int d = blockIdx.x * 4 + wave;
  if (d >= N) return;
  int j8 = lane >> 3, h = lane & 7;
  float edv = logits[(size_t)d * 16 + 8 + h];
  int beg = rowptr[d], end = rowptr[d + 1];
  float lsum = 0.f;
  for (int ii = beg + j8; ii < end; ii += 8) {
    unsigned s = edata[ii].x;
    float es = logits[(size_t)s * 16 + h];
    float lg = es + edv;
    lg = lg > 0.f ? lg : LRELU_ALPHA * lg;
    float p = __expf(fminf(lg, 80.f));
    lsum += p;
    pedge[(size_t)ii * 8 + h] = f2bf(p);
  }
  lsum += __shfl_xor(lsum, 8, 64);
  lsum += __shfl_xor(lsum, 16, 64);
  lsum += __shfl_xor(lsum, 32, 64);
  if (lane < 8) linv[(size_t)d * 8 + h] = lsum > 0.f ? 1.f / lsum : 0.f;
}

// =============================== bf16 MFMA GEMM ===============================
// C = A[M,K] @ BT[Ncols,K]^T.
// EPI: 0 plain, 1 max(acc, bf16 aux), 2 interleaved-xh write, 3 fp8(e4m3) byte write
template <int NT, int OUT_BF16, int EPI>
__global__ __launch_bounds__(256) void k_mgemm(const unsigned short* __restrict__ A, int lda,
                                               const unsigned short* __restrict__ BT, int ldb,
                                               void* __restrict__ Cv, int ldc,
                                               const void* __restrict__ aux,
                                               int M, int Ncols, int K) {
  __shared__ unsigned short As[64][64];
  __shared__ unsigned short Bs[NT * 16][64];
  int tid = threadIdx.x;
  int w = tid >> 6, lane = tid & 63;
  int quad = lane >> 4, l16 = lane & 15;
  int row0 = blockIdx.x * 64;
  int c0 = blockIdx.y * (NT * 16);
  float4v acc[NT];
#pragma unroll
  for (int t = 0; t < NT; ++t) acc[t] = (float4v){0.f, 0.f, 0.f, 0.f};

  for (int k0 = 0; k0 < K; k0 += 64) {
    __syncthreads();
#pragma unroll
    for (int i = 0; i < 2; ++i) {
      int c = tid + i * 256;
      int r = c >> 3, kc = c & 7;
      uint4 v = {0u, 0u, 0u, 0u};
      int gr = row0 + r;
      if (gr < M) v = *(const uint4*)(A + (size_t)gr * lda + k0 + kc * 8);
      *(uint4*)(&As[r][(kc ^ (r & 7)) * 8]) = v;
    }
#pragma unroll
    for (int i = 0; i < (NT * 128 + 255) / 256; ++i) {
      int c = tid + i * 256;
      if (c < NT * 128) {
        int n = c >> 3, kc = c & 7;
        uint4 v = {0u, 0u, 0u, 0u};
        int gn = c0 + n;
        if (gn < Ncols) v = *(const uint4*)(BT + (size_t)gn * ldb + k0 + kc * 8);
        *(uint4*)(&Bs[n][(kc ^ (n & 7)) * 8]) = v;
      }
    }
    __syncthreads();
#pragma unroll
    for (int ks = 0; ks < 2; ++ks) {
      int m = w * 16 + l16;
      int ga = (ks * 4 + quad) ^ (m & 7);
      short8 a = *(const short8*)(&As[m][ga * 8]);
#pragma unroll
      for (int t = 0; t < NT; ++t) {
        int n = t * 16 + l16;
        int gb = (ks * 4 + quad) ^ (n & 7);
        short8 b = *(const short8*)(&Bs[n][gb * 8]);
        acc[t] = __builtin_amdgcn_mfma_f32_16x16x32_bf16(a, b, acc[t], 0, 0, 0);
      }
    }
  }
#pragma unroll
  for (int t = 0; t < NT; ++t) {
    int cc = c0 + t * 16 + l16;
    if (cc >= Ncols) continue;
#pragma unroll
    for (int i = 0; i < 4; ++i) {
      int rr = row0 + w * 16 + quad * 4 + i;
      if (rr >= M) continue;
      float v = acc[t][i];
      if (EPI == 1) {
        unsigned short us = ((const unsigned short*)aux)[(size_t)rr * ldc + cc];
        v = fmaxf(v, bflo((unsigned)us));
      }
      if (EPI == 2) {
        // h1 -> xh interleaved: col cc -> 4*(cc>>1) + 2 + (cc&1)
        ((unsigned short*)Cv)[(size_t)rr * 256 + 4 * (cc >> 1) + 2 + (cc & 1)] = f2bf(v);
      } else if (EPI == 3) {
        int enc = __builtin_amdgcn_cvt_pk_fp8_f32(v, v, 0, false);
        ((unsigned char*)Cv)[(size_t)rr * ldc + cc] = (unsigned char)(enc & 0xff);
      } else if (OUT_BF16)
        ((unsigned short*)Cv)[(size_t)rr * ldc + cc] = f2bf(v);
      else
        ((float*)Cv)[(size_t)rr * ldc + cc] = v;
    }
  }
}

// =============================== Phase C: layer-0 aggregation (fp8 features) ==============
// feat8[N][256] bytes: byte group 4q..4q+3 = [fp8 GAT dims 2q,2q+1 | fp8 GCN dims 2q,2q+1].
// HALF-WAVE: lane2 reads uint2 (8 B = q groups 2*lane2, 2*lane2+1); halves alternate edges.
// 2x unrolled gather loop for MLP. Softmax denom inline from staged p.
__global__ __launch_bounds__(256) void k_agg0(const unsigned char* __restrict__ feat8,
                                              const int* __restrict__ rowptr,
                                              const uint2* __restrict__ edata,
                                              const unsigned short* __restrict__ pedge,
                                              unsigned short* __restrict__ x1c,
                                              unsigned short* __restrict__ x2,
                                              unsigned short* __restrict__ xh, int N) {
  __shared__ uint2 swl[4][64];
  __shared__ float pl[4][512];
  int wave = threadIdx.x >> 6, lane = threadIdx.x & 63;
  int d = blockIdx.x * 4 + wave;
  if (d >= N) return;
  int half = lane >> 5, lane2 = lane & 31;
  int head = lane2 >> 2;
  int beg = rowptr[d], end = rowptr[d + 1], deg = end - beg;
  f32x2 aa = {0.f, 0.f}, ab = {0.f, 0.f}, ga = {0.f, 0.f}, gb = {0.f, 0.f};
  float l = 0.f, wsum = 0.f;
  for (int base = 0; base < deg; base += 64) {
    int idx = beg + base + lane;
    uint2 sv = make_uint2(0u, 0u);
    uint4 q = make_uint4(0u, 0u, 0u, 0u);
    if (idx < end) {
      sv = edata[idx];
      q = *(const uint4*)(pedge + (size_t)idx * 8);
    }
    swl[wave][lane] = sv;
    float4 pa = make_float4(bflo(q.x), bfhi(q.x), bflo(q.y), bfhi(q.y));
    float4 pb = make_float4(bflo(q.z), bfhi(q.z), bflo(q.w), bfhi(q.w));
    *(float4*)&pl[wave][lane * 8] = pa;
    *(float4*)&pl[wave][lane * 8 + 4] = pb;
    int ng = deg - base; if (ng > 64) ng = 64;
    int tp = (ng + 1) >> 1;
    int t = 0;
    for (; t + 2 <= tp; t += 2) {
      int e0 = 2 * t + half, e1 = e0 + 2;
      uint2 sw0 = swl[wave][e0], sw1 = swl[wave][e1];
      float p0 = pl[wave][e0 * 8 + head], p1 = pl[wave][e1 * 8 + head];
      uint2 u0 = *(const uint2*)(feat8 + (size_t)sw0.x * 256 + 8 * lane2);
      uint2 u1 = *(const uint2*)(feat8 + (size_t)sw1.x * 256 + 8 * lane2);
      float w0 = __uint_as_float(sw0.y), w1 = __uint_as_float(sw1.y);
      f32x2 gA0 = __builtin_amdgcn_cvt_pk_f32_fp8(u0.x, false);
      f32x2 cA0 = __builtin_amdgcn_cvt_pk_f32_fp8(u0.x, true);
      f32x2 gB0 = __builtin_amdgcn_cvt_pk_f32_fp8(u0.y, false);
      f32x2 cB0 = __builtin_amdgcn_cvt_pk_f32_fp8(u0.y, true);
      aa += gA0 * p0; ga += cA0 * w0; ab += gB0 * p0; gb += cB0 * w0;
      l += p0; wsum += w0;
      f32x2 gA1 = __builtin_amdgcn_cvt_pk_f32_fp8(u1.x, false);
      f32x2 cA1 = __builtin_amdgcn_cvt_pk_f32_fp8(u1.x, true);
      f32x2 gB1 = __builtin_amdgcn_cvt_pk_f32_fp8(u1.y, false);
      f32x2 cB1 = __builtin_amdgcn_cvt_pk_f32_fp8(u1.y, true);
      aa += gA1 * p1; ga += cA1 * w1; ab += gB1 * p1; gb += cB1 * w1;
      l += p1; wsum += w1;
    }
    for (; t < tp; ++t) {
      int e = 2 * t + half;
      uint2 sw = swl[wave][e];
      float p = pl[wave][e * 8 + head];
      float wj = __uint_as_float(sw.y);
      uint2 u = *(const uint2*)(feat8 + (size_t)sw.x * 256 + 8 * lane2);
      f32x2 gA = __builtin_amdgcn_cvt_pk_f32_fp8(u.x, false);
      f32x2 cA = __builtin_amdgcn_cvt_pk_f32_fp8(u.x, true);
      f32x2 gB = __builtin_amdgcn_cvt_pk_f32_fp8(u.y, false);
      f32x2 cB = __builtin_amdgcn_cvt_pk_f32_fp8(u.y, true);
      aa += gA * p; ga += cA * wj; ab += gB * p; gb += cB * wj;
      l += p; wsum += wj;
    }
  }
  // combine halves
  aa.x += __shfl_xor(aa.x, 32, 64); aa.y += __shfl_xor(aa.y, 32, 64);
  ab.x += __shfl_xor(ab.x, 32, 64); ab.y += __shfl_xor(ab.y, 32, 64);
  ga.x += __shfl_xor(ga.x, 32, 64); ga.y += __shfl_xor(ga.y, 32, 64);
  gb.x += __shfl_xor(gb.x, 32, 64); gb.y += __shfl_xor(gb.y, 32, 64);
  l += __shfl_xor(l, 32, 64);
  wsum += __shfl_xor(wsum, 32, 64);
  if (half == 0) {
    float inv = l > 0.f ? 1.f / l : 0.f;
    float v0 = aa.x * inv, v1 = aa.y * inv, v2 = ab.x * inv, v3 = ab.y * inv;
    v0 = v0 > 0.f ? v0 : __expf(v0) - 1.f;  // ELU
    v1 = v1 > 0.f ? v1 : __expf(v1) - 1.f;
    v2 = v2 > 0.f ? v2 : __expf(v2) - 1.f;
    v3 = v3 > 0.f ? v3 : __expf(v3) - 1.f;
    unsigned p0 = packbf(v0, v1), p1 = packbf(v2, v3);
    ((uint2*)x1c)[(size_t)d * 32 + lane2] = make_uint2(p0, p1);
    ((unsigned*)xh)[(size_t)d * 128 + 4 * lane2] = p0;      // x-pair q=2*lane2
    ((unsigned*)xh)[(size_t)d * 128 + 4 * lane2 + 2] = p1;  // x-pair q+1
    float ginv = 1.f / fmaxf(wsum, 1e-16f);
    float w0 = fmaxf(ga.x * ginv, 0.f), w1 = fmaxf(ga.y * ginv, 0.f);
    float w2 = fmaxf(gb.x * ginv, 0.f), w3 = fmaxf(gb.y * ginv, 0.f);
    ((uint2*)x2)[(size_t)d * 32 + lane2] = make_uint2(packbf(w0, w1), packbf(w2, w3));
  }
}

// =============================== Phase E: layer-1 aggregation (dst-chunked) ==============
// HALF-WAVE: lane2 covers x-pairs q=2*lane2, 2*lane2+1 (+h1 pairs); halves alternate edges.
__global__ __launch_bounds__(256) void k_agg1(const unsigned short* __restrict__ xh,
                                              const int* __restrict__ rowptr,
                                              const uint2* __restrict__ edata,
                                              const unsigned short* __restrict__ pedge,
                                              const float* __restrict__ linv,
                                              unsigned short* __restrict__ aggbuf,
                                              unsigned short* __restrict__ x2f,
                                              int d0, int d1) {
  __shared__ uint2 swl[4][64];
  __shared__ float pl[4][512];
  int wave = threadIdx.x >> 6, lane = threadIdx.x & 63;
  int d = d0 + blockIdx.x * 4 + wave;
  if (d >= d1) return;
  int half = lane >> 5, lane2 = lane & 31;
  int beg = rowptr[d], end = rowptr[d + 1], deg = end - beg;
  f32x2 axA[8] = {}, axB[8] = {};
  f32x2 ga = {0.f, 0.f}, gb = {0.f, 0.f};
  float wsum = 0.f;
  for (int base = 0; base < deg; base += 64) {
    int idx = beg + base + lane;
    uint2 sv = make_uint2(0u, 0u);
    uint4 q = make_uint4(0u, 0u, 0u, 0u);
    if (idx < end) {
      sv = edata[idx];
      q = *(const uint4*)(pedge + (size_t)idx * 8);
    }
    swl[wave][lane] = sv;
    float4 pa = make_float4(bflo(q.x), bfhi(q.x), bflo(q.y), bfhi(q.y));
    float4 pb = make_float4(bflo(q.z), bfhi(q.z), bflo(q.w), bfhi(q.w));
    *(float4*)&pl[wave][lane * 8] = pa;
    *(float4*)&pl[wave][lane * 8 + 4] = pb;
    int ng = deg - base; if (ng > 64) ng = 64;
    int tp = (ng + 1) >> 1;
    for (int t = 0; t < tp; ++t) {
      int e = 2 * t + half;
      uint2 sw = swl[wave][e];
      float4 pv0 = *(const float4*)&pl[wave][e * 8];
      float4 pv1 = *(const float4*)&pl[wave][e * 8 + 4];
      float wj = __uint_as_float(sw.y);
      uint4 u = *(const uint4*)(xh + (size_t)sw.x * 256 + 8 * lane2);
      f32x2 xA = bfpair(u.x), hA = bfpair(u.y);
      f32x2 xB = bfpair(u.z), hB = bfpair(u.w);
      ga += hA * wj;
      gb += hB * wj;
      wsum += wj;
      axA[0] += xA * pv0.x; axB[0] += xB * pv0.x;
      axA[1] += xA * pv0.y; axB[1] += xB * pv0.y;
      axA[2] += xA * pv0.z; axB[2] += xB * pv0.z;
      axA[3] += xA * pv0.w; axB[3] += xB * pv0.w;
      axA[4] += xA * pv1.x; axB[4] += xB * pv1.x;
      axA[5] += xA * pv1.y; axB[5] += xB * pv1.y;
      axA[6] += xA * pv1.z; axB[6] += xB * pv1.z;
      axA[7] += xA * pv1.w; axB[7] += xB * pv1.w;
    }
  }
  // combine halves
#pragma unroll
  for (int h = 0; h < 8; ++h) {
    axA[h].x += __shfl_xor(axA[h].x, 32, 64); axA[h].y += __shfl_xor(axA[h].y, 32, 64);
    axB[h].x += __shfl_xor(axB[h].x, 32, 64); axB[h].y += __shfl_xor(axB[h].y, 32, 64);
  }
  ga.x += __shfl_xor(ga.x, 32, 64); ga.y += __shfl_xor(ga.y, 32, 64);
  gb.x += __shfl_xor(gb.x, 32, 64); gb.y += __shfl_xor(gb.y, 32, 64);
  wsum += __shfl_xor(wsum, 32, 64);
  if (half == 0) {
    float4 i0 = *(const float4*)(linv + (size_t)d * 8);
    float4 i1 = *(const float4*)(linv + (size_t)d * 8 + 4);
    float invh[8] = {i0.x, i0.y, i0.z, i0.w, i1.x, i1.y, i1.z, i1.w};
    size_t lr2 = (size_t)(d - d0) * 256;  // uint2 units
#pragma unroll
    for (int h = 0; h < 8; ++h) {
      ((uint2*)aggbuf)[lr2 + h * 32 + lane2] =
          make_uint2(packbf(axA[h].x * invh[h], axA[h].y * invh[h]),
                     packbf(axB[h].x * invh[h], axB[h].y * invh[h]));
    }
    float ginv = 1.f / fmaxf(wsum, 1e-16f);
    float w0 = fmaxf(ga.x * ginv, 0.f), w1 = fmaxf(ga.y * ginv, 0.f);
    float w2 = fmaxf(gb.x * ginv, 0.f), w3 = fmaxf(gb.y * ginv, 0.f);
    ((uint2*)x2f)[(size_t)d * 32 + lane2] = make_uint2(packbf(w0, w1), packbf(w2, w3));
  }
}

// =============================== host launch ===============================

extern "C" void kernel_launch(void* const* d_in, const int* in_sizes, int n_in,
                              void* d_out, int out_size, void* d_ws, size_t ws_size,
                              hipStream_t stream) {
  const float* x   = (const float*)d_in[0];
  const int*   ei  = (const int*)d_in[1];
  const float* ew  = (const float*)d_in[2];
  const float* W0  = (const float*)d_in[3];
  const float* a0s = (const float*)d_in[4];
  const float* a0d = (const float*)d_in[5];
  const float* W1  = (const float*)d_in[6];
  const float* a1s = (const float*)d_in[7];
  const float* a1d = (const float*)d_in[8];
  const float* gw0 = (const float*)d_in[9];
  const float* gw1 = (const float*)d_in[10];
  float* out = (float*)d_out;

  const int N = in_sizes[0] / 128;
  const int E = in_sizes[1] / 2;
  const int* src = ei;
  const int* dst = ei + E;

  // workspace carve (256B aligned); peak ~141 MB (< proven-safe 166 MB)
  char* p = (char*)d_ws;
  auto carve = [&](size_t bytes) {
    void* r = (void*)p;
    p += (bytes + 255) & ~(size_t)255;
    return r;
  };
  int*   cnt    = (int*)carve((size_t)N * 4);
  int*   rowptr = (int*)carve((size_t)(N + 1) * 4);
  int*   cur    = (int*)carve((size_t)N * 4);
  int*   bsum   = (int*)carve(256 * 4);
  uint2* edata  = (uint2*)carve((size_t)E * 8);
  unsigned short* W0catT  = (unsigned short*)carve(32768 * 2);
  float*          logitW  = (float*)carve(2048 * 4);
  unsigned short* gw1T    = (unsigned short*)carve(16384 * 2);
  unsigned short* va1T    = (unsigned short*)carve(2048 * 2);
  unsigned short* WstackT = (unsigned short*)carve(131072 * 2);
  unsigned short* x1c  = (unsigned short*)carve((size_t)N * 128 * 2);
  unsigned short* x2   = (unsigned short*)carve((size_t)N * 128 * 2);
  unsigned short* x2f  = (unsigned short*)carve((size_t)N * 128 * 2);
  float*          esed = (float*)carve((size_t)N * 16 * 4);
  unsigned short* xh   = (unsigned short*)carve((size_t)N * 256 * 2);
  unsigned short* pedge = (unsigned short*)carve((size_t)E * 8 * 2);  // layer0 then layer1
  float*          linv1 = (float*)carve((size_t)N * 8 * 4);
  // scratch union: {xb, feat8, logit0} then reused as aggbuf
  const int CH = 25600;
  size_t ph1 = ((size_t)N * 128 * 2 + 255) & ~(size_t)255;          // xb
  size_t ph2 = ph1 + (((size_t)N * 256 + 255) & ~(size_t)255);      // +feat8 (fp8 bytes)
  size_t ph3 = ph2 + (((size_t)N * 16 * 4 + 255) & ~(size_t)255);   // +logit0
  size_t scratch_sz = (size_t)CH * 1024 * 2;
  if (ph3 > scratch_sz) scratch_sz = ph3;
  char* scratch = (char*)carve(scratch_sz);
  unsigned short* xb     = (unsigned short*)scratch;
  unsigned char*  feat8  = (unsigned char*)(scratch + ph1);
  float*          logit0 = (float*)(scratch + ph2);
  unsigned short* aggbuf = (unsigned short*)scratch;  // alias, live after agg0

  int gE = (E + 255) / 256;
  int nb = (N + 1023) / 1024;
  int gM = (N + 63) / 64;
  int gD = (N + 3) / 4;

  // Phase A1: counts + scan (independent of weights)
  hipMemsetAsync(cnt, 0, (size_t)N * 4, stream);
  k_count<<<gE, 256, 0, stream>>>(dst, cnt, E);
  k_scan1<<<nb, 1024, 0, stream>>>(cnt, rowptr, bsum, N);
  k_scan2<<<1, 64, 0, stream>>>(bsum, rowptr + N, nb);
  k_scan3<<<nb, 1024, 0, stream>>>(rowptr, cur, bsum, N);

  // weight packing + fused x-cast/logit0 (before scatter: scatter consumes logit0)
  k_pack<<<(184320 + 255) / 256, 256, 0, stream>>>(W0, a0s, a0d, W1, a1s, a1d, gw0,
                                                   gw1, W0catT, logitW, gw1T, va1T,
                                                   WstackT);
  k_prep<<<(N + 15) / 16, 256, 0, stream>>>(x, logitW, xb, logit0, N);

  // Phase A2: scatter + fused layer-0 attention weights
  k_scatter<<<gE, 256, 0, stream>>>(src, dst, ew, logit0, cur, edata, pedge, E);

  // Phase B: feat8[N,256] fp8 (interleaved cols via W0catT row permutation)
  k_mgemm<8, 1, 3><<<dim3(gM, 2), 256, 0, stream>>>(xb, 128, W0catT, 128, feat8, 256,
                                                    nullptr, N, 256, 128);
  // Phase C: layer-0 GAT softmax-agg + ELU -> x1c & xh ; GCN agg + ReLU -> x2
  k_agg0<<<gD, 256, 0, stream>>>(feat8, rowptr, edata, pedge, x1c, x2, xh, N);

  // Phase D: esed[N,16] fp32 = x1c @ va1T^T ; h1 = x2 @ gw1T^T -> xh interleaved
  k_mgemm<1, 0, 0><<<dim3(gM, 1), 256, 0, stream>>>(x1c, 128, va1T, 128, esed, 16,
                                                    nullptr, N, 16, 128);
  k_mgemm<8, 1, 2><<<dim3(gM, 1), 256, 0, stream>>>(x2, 128, gw1T, 128, xh, 256,
                                                    nullptr, N, 128, 128);

  // layer-1 edge weights (pedge buffer reused)
  k_pedge<<<gD, 256, 0, stream>>>(esed, edata, rowptr, pedge, linv1, N);

  // Phase E/F: dst-chunked layer-1 aggregation + MFMA output GEMM (max-fused, bf16 aux)
  for (int d0 = 0; d0 < N; d0 += CH) {
    int d1 = d0 + CH < N ? d0 + CH : N;
    int chN = d1 - d0;
    k_agg1<<<(chN + 3) / 4, 256, 0, stream>>>(xh, rowptr, edata, pedge, linv1,
                                              aggbuf, x2f, d0, d1);
    k_mgemm<8, 0, 1><<<dim3((chN + 63) / 64, 1), 256, 0, stream>>>(
        aggbuf, 1024, WstackT, 1024, out + (size_t)d0 * 128, 128,
        x2f + (size_t)d0 * 128, chN, 128, 1024);
  }
}

// Round 11
// 451.402 us; speedup vs baseline: 1.1135x; 1.0280x over previous
//
#include <hip/hip_runtime.h>

#define LRELU_ALPHA 0.2f

typedef __attribute__((ext_vector_type(8))) short short8;
typedef __attribute__((ext_vector_type(4))) float float4v;
typedef __attribute__((ext_vector_type(2))) float f32x2;

__device__ __forceinline__ unsigned short f2bf(float f) {
  union { float f; unsigned u; } x; x.f = f;
  unsigned r = (x.u + 0x7fff + ((x.u >> 16) & 1)) >> 16;
  return (unsigned short)r;
}
__device__ __forceinline__ float bflo(unsigned u) {
  union { unsigned u; float f; } x; x.u = u << 16; return x.f;
}
__device__ __forceinline__ float bfhi(unsigned u) {
  union { unsigned u; float f; } x; x.u = u & 0xffff0000u; return x.f;
}
__device__ __forceinline__ f32x2 bfpair(unsigned u) {
  return (f32x2){bflo(u), bfhi(u)};
}
__device__ __forceinline__ unsigned packbf(float a, float b) {
  return (unsigned)f2bf(a) | ((unsigned)f2bf(b) << 16);
}

// =============================== Phase A: CSR build ===============================

__global__ __launch_bounds__(256) void k_count(const int* __restrict__ dst,
                                               int* __restrict__ cnt, int E) {
  int e = blockIdx.x * 256 + threadIdx.x;
  if (e < E) atomicAdd(&cnt[dst[e]], 1);
}

__global__ __launch_bounds__(1024) void k_scan1(const int* __restrict__ cnt,
                                                int* __restrict__ lscan,
                                                int* __restrict__ bsum, int N) {
  __shared__ int sm[1024];
  int t = threadIdx.x;
  int base = blockIdx.x * 1024;
  int v = (base + t < N) ? cnt[base + t] : 0;
  sm[t] = v;
  __syncthreads();
  for (int off = 1; off < 1024; off <<= 1) {
    int x = (t >= off) ? sm[t - off] : 0;
    __syncthreads();
    sm[t] += x;
    __syncthreads();
  }
  if (base + t < N) lscan[base + t] = sm[t] - v;
  if (t == 1023) bsum[blockIdx.x] = sm[1023];
}

// one-wave shfl scan (nb <= 64)
__global__ __launch_bounds__(64) void k_scan2(int* __restrict__ bsum,
                                              int* __restrict__ rowptrN, int nb) {
  int t = threadIdx.x;
  int v = (t < nb) ? bsum[t] : 0;
  int orig = v;
  for (int off = 1; off < 64; off <<= 1) {
    int y = __shfl_up(v, off, 64);
    if (t >= off) v += y;
  }
  if (t < nb) bsum[t] = v - orig;
  if (t == 63) *rowptrN = v;
}

__global__ __launch_bounds__(1024) void k_scan3(int* __restrict__ rowptr,
                                                int* __restrict__ cur,
                                                const int* __restrict__ bsum, int N) {
  int i = blockIdx.x * 1024 + threadIdx.x;
  if (i < N) {
    int v = rowptr[i] + bsum[blockIdx.x];
    rowptr[i] = v;
    cur[i] = v;
  }
}

// scatter + fused layer-0 attention weights; 4 edges/thread (pipelined atomics)
__global__ __launch_bounds__(256) void k_scatter(const int* __restrict__ src,
                                                 const int* __restrict__ dst,
                                                 const float* __restrict__ w,
                                                 const float* __restrict__ logit0,
                                                 int* __restrict__ cur,
                                                 uint2* __restrict__ edata,
                                                 unsigned short* __restrict__ pedge,
                                                 int E) {
  int base = (blockIdx.x * 256 + threadIdx.x) * 4;
  if (base >= E) return;
  int n = E - base; if (n > 4) n = 4;
  int ss[4], dd[4]; float ww[4];
  if (n == 4) {
    int4 s4 = *(const int4*)(src + base);
    int4 d4 = *(const int4*)(dst + base);
    float4 w4 = *(const float4*)(w + base);
    ss[0] = s4.x; ss[1] = s4.y; ss[2] = s4.z; ss[3] = s4.w;
    dd[0] = d4.x; dd[1] = d4.y; dd[2] = d4.z; dd[3] = d4.w;
    ww[0] = w4.x; ww[1] = w4.y; ww[2] = w4.z; ww[3] = w4.w;
  } else {
    for (int i = 0; i < n; ++i) { ss[i] = src[base + i]; dd[i] = dst[base + i]; ww[i] = w[base + i]; }
  }
  int pp[4];
#pragma unroll
  for (int i = 0; i < 4; ++i)
    if (i < n) pp[i] = atomicAdd(&cur[dd[i]], 1);
#pragma unroll
  for (int i = 0; i < 4; ++i) {
    if (i >= n) break;
    int s = ss[i], d = dd[i], p = pp[i];
    edata[p] = make_uint2((unsigned)s, __float_as_uint(ww[i]));
    float4 es0 = *(const float4*)(logit0 + (size_t)s * 16);
    float4 es1 = *(const float4*)(logit0 + (size_t)s * 16 + 4);
    float4 ed0 = *(const float4*)(logit0 + (size_t)d * 16 + 8);
    float4 ed1 = *(const float4*)(logit0 + (size_t)d * 16 + 12);
    float lg[8] = {es0.x + ed0.x, es0.y + ed0.y, es0.z + ed0.z, es0.w + ed0.w,
                   es1.x + ed1.x, es1.y + ed1.y, es1.z + ed1.z, es1.w + ed1.w};
    unsigned short o[8];
#pragma unroll
    for (int h = 0; h < 8; ++h) {
      float v = lg[h] > 0.f ? lg[h] : LRELU_ALPHA * lg[h];
      o[h] = f2bf(__expf(fminf(v, 80.f)));
    }
    ushort4 q0 = {o[0], o[1], o[2], o[3]};
    ushort4 q1 = {o[4], o[5], o[6], o[7]};
    *(ushort4*)(pedge + (size_t)p * 8) = q0;
    *(ushort4*)(pedge + (size_t)p * 8 + 4) = q1;
  }
}

// =============================== weight packing ===============================
// W0catT bf16 [256][128]: rows 0..127 GAT n=h*16+f -> W0[h,k,f]; rows 128..255 gcn_W0[k][n-128]
// logitW  fp32 [128][16] : c<8: va0_src[k][h=c]; c>=8: va0_dst[k][h=c-8]
// gw1T    bf16 [128][128]: gw1T[n][k] = gcn_W1[k][n]
// va1T    bf16 [16][128] : c<8: W1[h=c]@a1_src; c>=8: W1[h]@a1_dst
// WstackT bf16 [128][1024]: WstackT[n][h*128+k] = W1[h][k][n] * 0.125
__global__ __launch_bounds__(256) void k_pack(const float* __restrict__ W0,
                                              const float* __restrict__ a0s,
                                              const float* __restrict__ a0d,
                                              const float* __restrict__ W1,
                                              const float* __restrict__ a1s,
                                              const float* __restrict__ a1d,
                                              const float* __restrict__ gw0,
                                              const float* __restrict__ gw1,
                                              unsigned short* __restrict__ W0catT,
                                              float* __restrict__ logitW,
                                              unsigned short* __restrict__ gw1T,
                                              unsigned short* __restrict__ va1T,
                                              unsigned short* __restrict__ WstackT) {
  int idx = blockIdx.x * 256 + threadIdx.x;
  if (idx < 32768) {
    int n = idx >> 7, k = idx & 127;
    float v;
    if (n < 128) {
      int h = n >> 4, f = n & 15;
      v = W0[h * 2048 + k * 16 + f];
    } else {
      v = gw0[k * 128 + (n - 128)];
    }
    W0catT[idx] = f2bf(v);
  } else if (idx < 34816) {
    int j = idx - 32768;
    int k = j >> 4, c = j & 15;
    int h = (c < 8) ? c : c - 8;
    const float* a = (c < 8) ? a0s : a0d;
    float s = 0.f;
    for (int f = 0; f < 16; ++f) s += W0[h * 2048 + k * 16 + f] * a[h * 16 + f];
    logitW[j] = s;
  } else if (idx < 51200) {
    int j = idx - 34816;
    int n = j >> 7, k = j & 127;
    gw1T[j] = f2bf(gw1[k * 128 + n]);
  } else if (idx < 53248) {
    int j = idx - 51200;
    int c = j >> 7, k = j & 127;
    int h = c & 7;
    const float* a = (c < 8) ? a1s : a1d;
    float s = 0.f;
    for (int f = 0; f < 128; ++f) s += W1[h * 16384 + k * 128 + f] * a[h * 128 + f];
    va1T[j] = f2bf(s);
  } else if (idx < 184320) {
    int j = idx - 53248;
    int n = j >> 10, kk = j & 1023;
    int h = kk >> 7, k = kk & 127;
    WstackT[j] = f2bf(W1[h * 16384 + k * 128 + n] * 0.125f);
  }
}

// fused: xb = bf16(x), logit0[N,16] = x @ logitW; 16 rows per block
__global__ __launch_bounds__(256) void k_prep(const float* __restrict__ x,
                                              const float* __restrict__ logitW,
                                              unsigned short* __restrict__ xb,
                                              float* __restrict__ logit0, int N) {
  __shared__ float sm[16][132];
  __shared__ float sw[2048];
  int t = threadIdx.x;
  int base = blockIdx.x * 16;
  int r = t >> 4, cc = (t & 15) * 8;
  const float* xr = x + (size_t)(base + r) * 128 + cc;
  float4 v0 = *(const float4*)xr;
  float4 v1 = *(const float4*)(xr + 4);
  ushort4 o0 = {f2bf(v0.x), f2bf(v0.y), f2bf(v0.z), f2bf(v0.w)};
  ushort4 o1 = {f2bf(v1.x), f2bf(v1.y), f2bf(v1.z), f2bf(v1.w)};
  *(ushort4*)(xb + (size_t)(base + r) * 128 + cc) = o0;
  *(ushort4*)(xb + (size_t)(base + r) * 128 + cc + 4) = o1;
  *(float4*)&sm[r][cc] = v0;
  *(float4*)&sm[r][cc + 4] = v1;
  *(float4*)&sw[t * 8] = *(const float4*)(logitW + t * 8);
  *(float4*)&sw[t * 8 + 4] = *(const float4*)(logitW + t * 8 + 4);
  __syncthreads();
  int c = t & 15;
  float acc = 0.f;
#pragma unroll
  for (int k = 0; k < 128; ++k) acc += sm[r][k] * sw[k * 16 + c];
  logit0[(size_t)(base + r) * 16 + c] = acc;
}

// =============================== edge-weight precompute (layer 1) ===============================
__global__ __launch_bounds__(256) void k_pedge(const float* __restrict__ logits,
                                               const uint2* __restrict__ edata,
                                               const int* __restrict__ rowptr,
                                               unsigned short* __restrict__ pedge,
                                               float* __restrict__ linv, int N) {
  int wave = threadIdx.x >> 6, lane = threadIdx.x & 63;
  int d = blockIdx.x * 4 + wave;
  if (d >= N) return;
  int j8 = lane >> 3, h = lane & 7;
  float edv = logits[(size_t)d * 16 + 8 + h];
  int beg = rowptr[d], end = rowptr[d + 1];
  float lsum = 0.f;
  for (int ii = beg + j8; ii < end; ii += 8) {
    unsigned s = edata[ii].x;
    float es = logits[(size_t)s * 16 + h];
    float lg = es + edv;
    lg = lg > 0.f ? lg : LRELU_ALPHA * lg;
    float p = __expf(fminf(lg, 80.f));
    lsum += p;
    pedge[(size_t)ii * 8 + h] = f2bf(p);
  }
  lsum += __shfl_xor(lsum, 8, 64);
  lsum += __shfl_xor(lsum, 16, 64);
  lsum += __shfl_xor(lsum, 32, 64);
  if (lane < 8) linv[(size_t)d * 8 + h] = lsum > 0.f ? 1.f / lsum : 0.f;
}

// =============================== bf16 MFMA GEMM ===============================
// C = A[M,K] @ BT[Ncols,K]^T.
// EPI: 0 plain, 1 max(acc, bf16 aux), 2 interleaved-xh write,
//      4 split feat write: cc<128 -> bf16 Cv(featg, ld 128); cc>=128 -> fp8 aux(featc, ld 128)
template <int NT, int OUT_BF16, int EPI>
__global__ __launch_bounds__(256) void k_mgemm(const unsigned short* __restrict__ A, int lda,
                                               const unsigned short* __restrict__ BT, int ldb,
                                               void* __restrict__ Cv, int ldc,
                                               const void* __restrict__ aux,
                                               int M, int Ncols, int K) {
  __shared__ unsigned short As[64][64];
  __shared__ unsigned short Bs[NT * 16][64];
  int tid = threadIdx.x;
  int w = tid >> 6, lane = tid & 63;
  int quad = lane >> 4, l16 = lane & 15;
  int row0 = blockIdx.x * 64;
  int c0 = blockIdx.y * (NT * 16);
  float4v acc[NT];
#pragma unroll
  for (int t = 0; t < NT; ++t) acc[t] = (float4v){0.f, 0.f, 0.f, 0.f};

  for (int k0 = 0; k0 < K; k0 += 64) {
    __syncthreads();
#pragma unroll
    for (int i = 0; i < 2; ++i) {
      int c = tid + i * 256;
      int r = c >> 3, kc = c & 7;
      uint4 v = {0u, 0u, 0u, 0u};
      int gr = row0 + r;
      if (gr < M) v = *(const uint4*)(A + (size_t)gr * lda + k0 + kc * 8);
      *(uint4*)(&As[r][(kc ^ (r & 7)) * 8]) = v;
    }
#pragma unroll
    for (int i = 0; i < (NT * 128 + 255) / 256; ++i) {
      int c = tid + i * 256;
      if (c < NT * 128) {
        int n = c >> 3, kc = c & 7;
        uint4 v = {0u, 0u, 0u, 0u};
        int gn = c0 + n;
        if (gn < Ncols) v = *(const uint4*)(BT + (size_t)gn * ldb + k0 + kc * 8);
        *(uint4*)(&Bs[n][(kc ^ (n & 7)) * 8]) = v;
      }
    }
    __syncthreads();
#pragma unroll
    for (int ks = 0; ks < 2; ++ks) {
      int m = w * 16 + l16;
      int ga = (ks * 4 + quad) ^ (m & 7);
      short8 a = *(const short8*)(&As[m][ga * 8]);
#pragma unroll
      for (int t = 0; t < NT; ++t) {
        int n = t * 16 + l16;
        int gb = (ks * 4 + quad) ^ (n & 7);
        short8 b = *(const short8*)(&Bs[n][gb * 8]);
        acc[t] = __builtin_amdgcn_mfma_f32_16x16x32_bf16(a, b, acc[t], 0, 0, 0);
      }
    }
  }
#pragma unroll
  for (int t = 0; t < NT; ++t) {
    int cc = c0 + t * 16 + l16;
    if (cc >= Ncols) continue;
#pragma unroll
    for (int i = 0; i < 4; ++i) {
      int rr = row0 + w * 16 + quad * 4 + i;
      if (rr >= M) continue;
      float v = acc[t][i];
      if (EPI == 1) {
        unsigned short us = ((const unsigned short*)aux)[(size_t)rr * ldc + cc];
        v = fmaxf(v, bflo((unsigned)us));
      }
      if (EPI == 2) {
        // h1 -> xh interleaved: col cc -> 4*(cc>>1) + 2 + (cc&1)
        ((unsigned short*)Cv)[(size_t)rr * 256 + 4 * (cc >> 1) + 2 + (cc & 1)] = f2bf(v);
      } else if (EPI == 4) {
        if (cc < 128) {
          ((unsigned short*)Cv)[(size_t)rr * 128 + cc] = f2bf(v);
        } else {
          int enc = __builtin_amdgcn_cvt_pk_fp8_f32(v, v, 0, false);
          ((unsigned char*)aux)[(size_t)rr * 128 + (cc - 128)] = (unsigned char)(enc & 0xff);
        }
      } else if (OUT_BF16)
        ((unsigned short*)Cv)[(size_t)rr * ldc + cc] = f2bf(v);
      else
        ((float*)Cv)[(size_t)rr * ldc + cc] = v;
    }
  }
}

// =============================== Phase C: layer-0 aggregation (split tables) ==============
// featg bf16 [N][128] (GAT Wh0), featc fp8 [N][128] (GCN h0).
// HALF-WAVE: lane2 covers dims 4*lane2..+3; halves alternate edges; 2x unroll.
__global__ __launch_bounds__(256) void k_agg0(const unsigned short* __restrict__ featg,
                                              const unsigned char* __restrict__ featc,
                                              const int* __restrict__ rowptr,
                                              const uint2* __restrict__ edata,
                                              const unsigned short* __restrict__ pedge,
                                              unsigned short* __restrict__ x1c,
                                              unsigned short* __restrict__ x2,
                                              unsigned short* __restrict__ xh, int N) {
  __shared__ uint2 swl[4][64];
  __shared__ float pl[4][512];
  int wave = threadIdx.x >> 6, lane = threadIdx.x & 63;
  int d = blockIdx.x * 4 + wave;
  if (d >= N) return;
  int half = lane >> 5, lane2 = lane & 31;
  int head = lane2 >> 2;
  int beg = rowptr[d], end = rowptr[d + 1], deg = end - beg;
  f32x2 aa = {0.f, 0.f}, ab = {0.f, 0.f}, ga = {0.f, 0.f}, gb = {0.f, 0.f};
  float l = 0.f, wsum = 0.f;
  for (int base = 0; base < deg; base += 64) {
    int idx = beg + base + lane;
    uint2 sv = make_uint2(0u, 0u);
    uint4 q = make_uint4(0u, 0u, 0u, 0u);
    if (idx < end) {
      sv = edata[idx];
      q = *(const uint4*)(pedge + (size_t)idx * 8);
    }
    swl[wave][lane] = sv;
    float4 pa = make_float4(bflo(q.x), bfhi(q.x), bflo(q.y), bfhi(q.y));
    float4 pb = make_float4(bflo(q.z), bfhi(q.z), bflo(q.w), bfhi(q.w));
    *(float4*)&pl[wave][lane * 8] = pa;
    *(float4*)&pl[wave][lane * 8 + 4] = pb;
    int ng = deg - base; if (ng > 64) ng = 64;
    int tp = (ng + 1) >> 1;
    int t = 0;
    for (; t + 2 <= tp; t += 2) {
      int e0 = 2 * t + half, e1 = e0 + 2;
      uint2 sw0 = swl[wave][e0], sw1 = swl[wave][e1];
      float p0 = pl[wave][e0 * 8 + head], p1 = pl[wave][e1 * 8 + head];
      uint2 g0 = ((const uint2*)featg)[(size_t)sw0.x * 32 + lane2];
      unsigned c0v = ((const unsigned*)featc)[(size_t)sw0.x * 32 + lane2];
      uint2 g1 = ((const uint2*)featg)[(size_t)sw1.x * 32 + lane2];
      unsigned c1v = ((const unsigned*)featc)[(size_t)sw1.x * 32 + lane2];
      float w0 = __uint_as_float(sw0.y), w1 = __uint_as_float(sw1.y);
      aa += bfpair(g0.x) * p0;
      ab += bfpair(g0.y) * p0;
      ga += __builtin_amdgcn_cvt_pk_f32_fp8(c0v, false) * w0;
      gb += __builtin_amdgcn_cvt_pk_f32_fp8(c0v, true) * w0;
      l += p0; wsum += w0;
      aa += bfpair(g1.x) * p1;
      ab += bfpair(g1.y) * p1;
      ga += __builtin_amdgcn_cvt_pk_f32_fp8(c1v, false) * w1;
      gb += __builtin_amdgcn_cvt_pk_f32_fp8(c1v, true) * w1;
      l += p1; wsum += w1;
    }
    for (; t < tp; ++t) {
      int e = 2 * t + half;
      uint2 sw = swl[wave][e];
      float p = pl[wave][e * 8 + head];
      float wj = __uint_as_float(sw.y);
      uint2 g = ((const uint2*)featg)[(size_t)sw.x * 32 + lane2];
      unsigned cv = ((const unsigned*)featc)[(size_t)sw.x * 32 + lane2];
      aa += bfpair(g.x) * p;
      ab += bfpair(g.y) * p;
      ga += __builtin_amdgcn_cvt_pk_f32_fp8(cv, false) * wj;
      gb += __builtin_amdgcn_cvt_pk_f32_fp8(cv, true) * wj;
      l += p; wsum += wj;
    }
  }
  // combine halves
  aa.x += __shfl_xor(aa.x, 32, 64); aa.y += __shfl_xor(aa.y, 32, 64);
  ab.x += __shfl_xor(ab.x, 32, 64); ab.y += __shfl_xor(ab.y, 32, 64);
  ga.x += __shfl_xor(ga.x, 32, 64); ga.y += __shfl_xor(ga.y, 32, 64);
  gb.x += __shfl_xor(gb.x, 32, 64); gb.y += __shfl_xor(gb.y, 32, 64);
  l += __shfl_xor(l, 32, 64);
  wsum += __shfl_xor(wsum, 32, 64);
  if (half == 0) {
    float inv = l > 0.f ? 1.f / l : 0.f;
    float v0 = aa.x * inv, v1 = aa.y * inv, v2 = ab.x * inv, v3 = ab.y * inv;
    v0 = v0 > 0.f ? v0 : __expf(v0) - 1.f;  // ELU
    v1 = v1 > 0.f ? v1 : __expf(v1) - 1.f;
    v2 = v2 > 0.f ? v2 : __expf(v2) - 1.f;
    v3 = v3 > 0.f ? v3 : __expf(v3) - 1.f;
    unsigned p0 = packbf(v0, v1), p1 = packbf(v2, v3);
    ((uint2*)x1c)[(size_t)d * 32 + lane2] = make_uint2(p0, p1);
    ((unsigned*)xh)[(size_t)d * 128 + 4 * lane2] = p0;      // x-pair q=2*lane2
    ((unsigned*)xh)[(size_t)d * 128 + 4 * lane2 + 2] = p1;  // x-pair q+1
    float ginv = 1.f / fmaxf(wsum, 1e-16f);
    float w0 = fmaxf(ga.x * ginv, 0.f), w1 = fmaxf(ga.y * ginv, 0.f);
    float w2 = fmaxf(gb.x * ginv, 0.f), w3 = fmaxf(gb.y * ginv, 0.f);
    ((uint2*)x2)[(size_t)d * 32 + lane2] = make_uint2(packbf(w0, w1), packbf(w2, w3));
  }
}

// =============================== Phase E: layer-1 aggregation (single pass) ==============
// HALF-WAVE: lane2 covers x-pairs q=2*lane2, 2*lane2+1 (+h1 pairs); halves alternate edges.
__global__ __launch_bounds__(256) void k_agg1(const unsigned short* __restrict__ xh,
                                              const int* __restrict__ rowptr,
                                              const uint2* __restrict__ edata,
                                              const unsigned short* __restrict__ pedge,
                                              const float* __restrict__ linv,
                                              unsigned short* __restrict__ aggbuf,
                                              unsigned short* __restrict__ x2f, int N) {
  __shared__ uint2 swl[4][64];
  __shared__ float pl[4][512];
  int wave = threadIdx.x >> 6, lane = threadIdx.x & 63;
  int d = blockIdx.x * 4 + wave;
  if (d >= N) return;
  int half = lane >> 5, lane2 = lane & 31;
  int beg = rowptr[d], end = rowptr[d + 1], deg = end - beg;
  f32x2 axA[8] = {}, axB[8] = {};
  f32x2 ga = {0.f, 0.f}, gb = {0.f, 0.f};
  float wsum = 0.f;
  for (int base = 0; base < deg; base += 64) {
    int idx = beg + base + lane;
    uint2 sv = make_uint2(0u, 0u);
    uint4 q = make_uint4(0u, 0u, 0u, 0u);
    if (idx < end) {
      sv = edata[idx];
      q = *(const uint4*)(pedge + (size_t)idx * 8);
    }
    swl[wave][lane] = sv;
    float4 pa = make_float4(bflo(q.x), bfhi(q.x), bflo(q.y), bfhi(q.y));
    float4 pb = make_float4(bflo(q.z), bfhi(q.z), bflo(q.w), bfhi(q.w));
    *(float4*)&pl[wave][lane * 8] = pa;
    *(float4*)&pl[wave][lane * 8 + 4] = pb;
    int ng = deg - base; if (ng > 64) ng = 64;
    int tp = (ng + 1) >> 1;
    for (int t = 0; t < tp; ++t) {
      int e = 2 * t + half;
      uint2 sw = swl[wave][e];
      float4 pv0 = *(const float4*)&pl[wave][e * 8];
      float4 pv1 = *(const float4*)&pl[wave][e * 8 + 4];
      float wj = __uint_as_float(sw.y);
      uint4 u = *(const uint4*)(xh + (size_t)sw.x * 256 + 8 * lane2);
      f32x2 xA = bfpair(u.x), hA = bfpair(u.y);
      f32x2 xB = bfpair(u.z), hB = bfpair(u.w);
      ga += hA * wj;
      gb += hB * wj;
      wsum += wj;
      axA[0] += xA * pv0.x; axB[0] += xB * pv0.x;
      axA[1] += xA * pv0.y; axB[1] += xB * pv0.y;
      axA[2] += xA * pv0.z; axB[2] += xB * pv0.z;
      axA[3] += xA * pv0.w; axB[3] += xB * pv0.w;
      axA[4] += xA * pv1.x; axB[4] += xB * pv1.x;
      axA[5] += xA * pv1.y; axB[5] += xB * pv1.y;
      axA[6] += xA * pv1.z; axB[6] += xB * pv1.z;
      axA[7] += xA * pv1.w; axB[7] += xB * pv1.w;
    }
  }
  // combine halves
#pragma unroll
  for (int h = 0; h < 8; ++h) {
    axA[h].x += __shfl_xor(axA[h].x, 32, 64); axA[h].y += __shfl_xor(axA[h].y, 32, 64);
    axB[h].x += __shfl_xor(axB[h].x, 32, 64); axB[h].y += __shfl_xor(axB[h].y, 32, 64);
  }
  ga.x += __shfl_xor(ga.x, 32, 64); ga.y += __shfl_xor(ga.y, 32, 64);
  gb.x += __shfl_xor(gb.x, 32, 64); gb.y += __shfl_xor(gb.y, 32, 64);
  wsum += __shfl_xor(wsum, 32, 64);
  if (half == 0) {
    float4 i0 = *(const float4*)(linv + (size_t)d * 8);
    float4 i1 = *(const float4*)(linv + (size_t)d * 8 + 4);
    float invh[8] = {i0.x, i0.y, i0.z, i0.w, i1.x, i1.y, i1.z, i1.w};
    size_t lr2 = (size_t)d * 256;  // uint2 units
#pragma unroll
    for (int h = 0; h < 8; ++h) {
      ((uint2*)aggbuf)[lr2 + h * 32 + lane2] =
          make_uint2(packbf(axA[h].x * invh[h], axA[h].y * invh[h]),
                     packbf(axB[h].x * invh[h], axB[h].y * invh[h]));
    }
    float ginv = 1.f / fmaxf(wsum, 1e-16f);
    float w0 = fmaxf(ga.x * ginv, 0.f), w1 = fmaxf(ga.y * ginv, 0.f);
    float w2 = fmaxf(gb.x * ginv, 0.f), w3 = fmaxf(gb.y * ginv, 0.f);
    ((uint2*)x2f)[(size_t)d * 32 + lane2] = make_uint2(packbf(w0, w1), packbf(w2, w3));
  }
}

// =============================== host launch ===============================

extern "C" void kernel_launch(void* const* d_in, const int* in_sizes, int n_in,
                              void* d_out, int out_size, void* d_ws, size_t ws_size,
                              hipStream_t stream) {
  const float* x   = (const float*)d_in[0];
  const int*   ei  = (const int*)d_in[1];
  const float* ew  = (const float*)d_in[2];
  const float* W0  = (const float*)d_in[3];
  const float* a0s = (const float*)d_in[4];
  const float* a0d = (const float*)d_in[5];
  const float* W1  = (const float*)d_in[6];
  const float* a1s = (const float*)d_in[7];
  const float* a1d = (const float*)d_in[8];
  const float* gw0 = (const float*)d_in[9];
  const float* gw1 = (const float*)d_in[10];
  float* out = (float*)d_out;

  const int N = in_sizes[0] / 128;
  const int E = in_sizes[1] / 2;
  const int* src = ei;
  const int* dst = ei + E;

  // workspace carve (256B aligned); peak ~166 MB (= round-2's proven-safe 169 MB envelope)
  char* p = (char*)d_ws;
  auto carve = [&](size_t bytes) {
    void* r = (void*)p;
    p += (bytes + 255) & ~(size_t)255;
    return r;
  };
  int*   cnt    = (int*)carve((size_t)N * 4);
  int*   rowptr = (int*)carve((size_t)(N + 1) * 4);
  int*   cur    = (int*)carve((size_t)N * 4);
  int*   bsum   = (int*)carve(256 * 4);
  uint2* edata  = (uint2*)carve((size_t)E * 8);
  unsigned short* W0catT  = (unsigned short*)carve(32768 * 2);
  float*          logitW  = (float*)carve(2048 * 4);
  unsigned short* gw1T    = (unsigned short*)carve(16384 * 2);
  unsigned short* va1T    = (unsigned short*)carve(2048 * 2);
  unsigned short* WstackT = (unsigned short*)carve(131072 * 2);
  unsigned short* x2   = (unsigned short*)carve((size_t)N * 128 * 2);  // reused as x2f
  float*          esed = (float*)carve((size_t)N * 16 * 4);
  unsigned short* xh   = (unsigned short*)carve((size_t)N * 256 * 2);
  unsigned short* pedge = (unsigned short*)carve((size_t)E * 8 * 2);  // layer0 then layer1
  float*          linv1 = (float*)carve((size_t)N * 8 * 4);
  // scratch union: phase1 {xb | featg | featc | logit0}; x1c aliases xb after phase B;
  // aggbuf [N,1024] bf16 overwrites all after phase D.
  size_t ph1 = ((size_t)N * 128 * 2 + 255) & ~(size_t)255;          // xb / x1c
  size_t ph2 = ph1 + (((size_t)N * 128 * 2 + 255) & ~(size_t)255);  // +featg
  size_t ph3 = ph2 + (((size_t)N * 128 + 255) & ~(size_t)255);      // +featc
  size_t ph4 = ph3 + (((size_t)N * 16 * 4 + 255) & ~(size_t)255);   // +logit0
  size_t scratch_sz = (size_t)N * 1024 * 2;  // aggbuf
  if (ph4 > scratch_sz) scratch_sz = ph4;
  char* scratch = (char*)carve(scratch_sz);
  unsigned short* xb     = (unsigned short*)scratch;
  unsigned short* x1c    = (unsigned short*)scratch;  // alias of xb (dead after phase B)
  unsigned short* featg  = (unsigned short*)(scratch + ph1);
  unsigned char*  featc  = (unsigned char*)(scratch + ph2);
  float*          logit0 = (float*)(scratch + ph3);
  unsigned short* aggbuf = (unsigned short*)scratch;  // alias, live after phase D
  unsigned short* x2f    = x2;                        // alias (x2 dead after phase D)

  int gE = (E + 255) / 256;
  int gE4 = ((E + 3) / 4 + 255) / 256;
  int nb = (N + 1023) / 1024;
  int gM = (N + 63) / 64;
  int gD = (N + 3) / 4;

  // Phase A1: counts + scan (independent of weights)
  hipMemsetAsync(cnt, 0, (size_t)N * 4, stream);
  k_count<<<gE, 256, 0, stream>>>(dst, cnt, E);
  k_scan1<<<nb, 1024, 0, stream>>>(cnt, rowptr, bsum, N);
  k_scan2<<<1, 64, 0, stream>>>(bsum, rowptr + N, nb);
  k_scan3<<<nb, 1024, 0, stream>>>(rowptr, cur, bsum, N);

  // weight packing + fused x-cast/logit0 (before scatter: scatter consumes logit0)
  k_pack<<<(184320 + 255) / 256, 256, 0, stream>>>(W0, a0s, a0d, W1, a1s, a1d, gw0,
                                                   gw1, W0catT, logitW, gw1T, va1T,
                                                   WstackT);
  k_prep<<<(N + 15) / 16, 256, 0, stream>>>(x, logitW, xb, logit0, N);

  // Phase A2: scatter (4 edges/thread) + fused layer-0 attention weights
  k_scatter<<<gE4, 256, 0, stream>>>(src, dst, ew, logit0, cur, edata, pedge, E);

  // Phase B: featg[N,128] bf16 + featc[N,128] fp8
  k_mgemm<8, 1, 4><<<dim3(gM, 2), 256, 0, stream>>>(xb, 128, W0catT, 128, featg, 128,
                                                    featc, N, 256, 128);
  // Phase C: layer-0 GAT softmax-agg + ELU -> x1c & xh ; GCN agg + ReLU -> x2
  k_agg0<<<gD, 256, 0, stream>>>(featg, featc, rowptr, edata, pedge, x1c, x2, xh, N);

  // Phase D: esed[N,16] fp32 = x1c @ va1T^T ; h1 = x2 @ gw1T^T -> xh interleaved
  k_mgemm<1, 0, 0><<<dim3(gM, 1), 256, 0, stream>>>(x1c, 128, va1T, 128, esed, 16,
                                                    nullptr, N, 16, 128);
  k_mgemm<8, 1, 2><<<dim3(gM, 1), 256, 0, stream>>>(x2, 128, gw1T, 128, xh, 256,
                                                    nullptr, N, 128, 128);

  // layer-1 edge weights (pedge buffer reused)
  k_pedge<<<gD, 256, 0, stream>>>(esed, edata, rowptr, pedge, linv1, N);

  // Phase E: single-pass layer-1 aggregation -> aggbuf [N,1024] bf16, x2f
  k_agg1<<<gD, 256, 0, stream>>>(xh, rowptr, edata, pedge, linv1, aggbuf, x2f, N);

  // Phase F: out = max(aggbuf @ WstackT^T, x2f)
  k_mgemm<8, 0, 1><<<dim3(gM, 1), 256, 0, stream>>>(aggbuf, 1024, WstackT, 1024, out,
                                                    128, x2f, N, 128, 1024);
}